// Round 9
// baseline (3338.605 us; speedup 1.0000x reference)
//
#include <hip/hip_runtime.h>
#include <stdint.h>

#define E_ 3
#define C_ 2
#define N_ 2048
#define B_ 64
#define T_ 50
#define WIN_ 256
#define WOUT_ 256
#define U_ 512
#define BT_ (B_*T_)
#define BTP_ 3328

typedef unsigned short u16;
typedef unsigned int u32;
typedef __bf16 bf16x8 __attribute__((ext_vector_type(8)));
typedef float f32x4 __attribute__((ext_vector_type(4)));

#define NN_ (2048LL*2048LL)

__device__ __forceinline__ float bf2f(u16 u){
  u32 x = ((u32)u) << 16; return __builtin_bit_cast(float, x);
}
__device__ __forceinline__ u16 f2bf(float f){
  u32 x = __builtin_bit_cast(u32, f);
  u32 r = (x + 0x7fffu + ((x >> 16) & 1u)) >> 16;
  return (u16)r;
}

__device__ __forceinline__ void gload16(const u16* g, u16* l){
  __builtin_amdgcn_global_load_lds((const __attribute__((address_space(1))) u32*)g,
                                   (__attribute__((address_space(3))) u32*)l, 16, 0, 0);
}

// ---------------- prep0: softmax filters + bsum ----------------
__global__ void k_prep0(const float* __restrict__ w1, const float* __restrict__ w2,
                        const float* __restrict__ w3, float* __restrict__ filt,
                        const float* __restrict__ bih, const float* __restrict__ bhh,
                        float* __restrict__ bsum){
  const int i = blockIdx.x*256 + threadIdx.x;
  bsum[i] = bih[i] + bhh[i];
  if(blockIdx.x==0 && threadIdx.x < 3*C_){
    const int t = threadIdx.x;
    const int fi = t / C_, c = t % C_;
    const float* w = (fi==0) ? w1 : ((fi==1) ? w2 : w3);
    float v[E_]; float mx = -3.4e38f;
    for(int e=0;e<E_;e++){ v[e] = w[c*E_+e]; mx = fmaxf(mx, v[e]); }
    float s = 0.f;
    for(int e=0;e<E_;e++){ v[e] = expf(v[e]-mx); s += v[e]; }
    for(int e=0;e<E_;e++) filt[(fi*C_+c)*E_ + e] = v[e]/s;
  }
}

// ---------------- fused combine: HA (direct) + HBt (transposed), A read ONCE ----------------
__global__ void k_combineAll(const float* __restrict__ A, const float* __restrict__ filt,
                             u16* __restrict__ HA, u16* __restrict__ HBt){
  __shared__ float te[3][32][33];
  const int ti = blockIdx.x, tj = blockIdx.y;
  const int x = threadIdx.x, y0 = threadIdx.y;
  #pragma unroll
  for(int i=0;i<4;i++){
    const int y = y0 + i*8;
    const long base = (long)(tj*32+y)*N_ + ti*32 + x;
    const float a0 = A[0*NN_+base], a1 = A[1*NN_+base], a2 = A[2*NN_+base];
    te[0][y][x]=a0; te[1][y][x]=a1; te[2][y][x]=a2;
    #pragma unroll
    for(int c=0;c<C_;c++)
      HA[c*NN_ + base] = f2bf(filt[c*E_]*a0 + filt[c*E_+1]*a1 + filt[c*E_+2]*a2);
  }
  __syncthreads();
  #pragma unroll
  for(int i=0;i<4;i++){
    const int y = y0 + i*8;
    const long ob = (long)(ti*32+y)*N_ + tj*32 + x;
    const float a0=te[0][x][y], a1=te[1][x][y], a2=te[2][x][y];
    #pragma unroll
    for(int c=0;c<C_;c++)
      HBt[c*NN_+ob] = f2bf(filt[(C_+c)*E_]*a0 + filt[(C_+c)*E_+1]*a1 + filt[(C_+c)*E_+2]*a2);
  }
}

// ---------------- HB2t both channels, one pass over A ----------------
__global__ void k_combineT2(const float* __restrict__ A, const float* __restrict__ f,
                            u16* __restrict__ outp){
  __shared__ float te[3][32][33];
  const int ti = blockIdx.x, tj = blockIdx.y;
  const int x = threadIdx.x, y0 = threadIdx.y;
  #pragma unroll
  for(int i=0;i<4;i++){
    const int y = y0 + i*8;
    const long base = (long)(tj*32+y)*N_ + ti*32 + x;
    te[0][y][x]=A[0*NN_+base]; te[1][y][x]=A[1*NN_+base]; te[2][y][x]=A[2*NN_+base];
  }
  __syncthreads();
  #pragma unroll
  for(int i=0;i<4;i++){
    const int y = y0 + i*8;
    const long ob = (long)(ti*32+y)*N_ + tj*32 + x;
    const float a0=te[0][x][y], a1=te[1][x][y], a2=te[2][x][y];
    #pragma unroll
    for(int c=0;c<C_;c++)
      outp[c*NN_+ob] = f2bf(f[c*E_]*a0 + f[c*E_+1]*a1 + f[c*E_+2]*a2);
  }
}

// ---------------- MFMA GEMM: OUT[i][j] = sum_k A[i][k]*B[j][k] ----------------
// MODE 1: bf16 raw; 2: bf16 relu(dis[row]*acc+bias[col]); 3: f32 acc+bias[col];
// MODE 4: Gq scatter; MODE 5: bf16 (acc + (row==col)) * disv[col]  (fused Pd)
template<int MODE>
__global__ __launch_bounds__(256) void gemm_bt(
    const u16* __restrict__ Ag, const u16* __restrict__ Bg, void* __restrict__ Cg,
    int K, int ldc, long sA, long sB, long sC,
    const float* __restrict__ disv, int sDis, const float* __restrict__ bias)
{
  __shared__ u16 At[128*32];
  __shared__ u16 Bt[128*32];
  const int tid = threadIdx.x;
  const int w = tid >> 6, l = tid & 63;
  const int z = blockIdx.z;
  const u16* Ab = Ag + (long)z*sA;
  const u16* Bb = Bg + (long)z*sB;
  const int rowBase = blockIdx.y*128;
  const int colBase = blockIdx.x*128;

  f32x4 acc[4][4];
  #pragma unroll
  for(int i=0;i<4;i++)
    #pragma unroll
    for(int j=0;j<4;j++)
      acc[i][j] = f32x4{0.f,0.f,0.f,0.f};

  const int wr = w >> 1, wc = w & 1;
  const int arow0 = (w*2+0)*16 + (l>>2);
  const int arow1 = (w*2+1)*16 + (l>>2);
  const int kc = (((l&3) ^ ((l>>2)&3)))*8;
  const int frow = l & 15;
  const int fkc = l >> 4;

  const int nk = K >> 5;
  for(int kt=0; kt<nk; ++kt){
    const int k0 = kt << 5;
    gload16(Ab + (long)(rowBase+arow0)*K + k0 + kc, &At[(w*2+0)*512]);
    gload16(Ab + (long)(rowBase+arow1)*K + k0 + kc, &At[(w*2+1)*512]);
    gload16(Bb + (long)(colBase+arow0)*K + k0 + kc, &Bt[(w*2+0)*512]);
    gload16(Bb + (long)(colBase+arow1)*K + k0 + kc, &Bt[(w*2+1)*512]);
    __syncthreads();
    bf16x8 af[4], bfv[4];
    #pragma unroll
    for(int m=0;m<4;m++){
      const int rr = wr*64 + m*16 + frow;
      af[m] = *(const bf16x8*)&At[rr*32 + ((fkc ^ (rr&3))<<3)];
    }
    #pragma unroll
    for(int n=0;n<4;n++){
      const int rr = wc*64 + n*16 + frow;
      bfv[n] = *(const bf16x8*)&Bt[rr*32 + ((fkc ^ (rr&3))<<3)];
    }
    #pragma unroll
    for(int m=0;m<4;m++)
      #pragma unroll
      for(int n=0;n<4;n++)
        acc[m][n] = __builtin_amdgcn_mfma_f32_16x16x32_bf16(af[m], bfv[n], acc[m][n], 0, 0, 0);
    __syncthreads();
  }

  #pragma unroll
  for(int m=0;m<4;m++){
    const int row0 = rowBase + wr*64 + m*16 + (l>>4)*4;
    #pragma unroll
    for(int n=0;n<4;n++){
      const int col = colBase + wc*64 + n*16 + (l&15);
      #pragma unroll
      for(int r=0;r<4;r++){
        const float v = acc[m][n][r];
        if(MODE==1){
          ((u16*)Cg)[z*sC + (long)(row0+r)*ldc + col] = f2bf(v);
        } else if(MODE==2){
          float o = disv[z*(long)sDis + row0 + r]*v + bias[col];
          o = o > 0.f ? o : 0.f;
          ((u16*)Cg)[z*sC + (long)(row0+r)*ldc + col] = f2bf(o);
        } else if(MODE==3){
          ((float*)Cg)[z*sC + (long)(row0+r)*ldc + col] = v + bias[col];
        } else if(MODE==4){
          const int row = row0 + r;
          if(row < BT_){
            const int bb = row/50, tt = row - bb*50;
            const int gq = col >> 9, ugg = col & 511;
            ((float*)Cg)[((((long)tt*4 + (bb>>4))*512 + ugg)*16 + (bb&15))*4 + gq] = v + bias[col];
          }
        } else if(MODE==5){
          const int row = row0 + r;
          const float o = (v + (row==col ? 1.f : 0.f)) * disv[z*(long)sDis + col];
          ((u16*)Cg)[z*sC + (long)row*ldc + col] = f2bf(o);
        }
      }
    }
  }
}

// ---------------- column-degree partial sums ----------------
__global__ void k_degpart(const u16* __restrict__ H, float* __restrict__ partial){
  const int c = blockIdx.z;
  const int col = blockIdx.x*256 + threadIdx.x;
  const int r0 = blockIdx.y*128;
  const u16* Hc = H + c*NN_;
  float s = 0.f;
  #pragma unroll 4
  for(int r=0;r<128;r++) s += bf2f(Hc[(long)(r0+r)*N_ + col]);
  partial[((long)c*16 + blockIdx.y)*N_ + col] = s;
}

// ---------------- dinv[c][m] = 1/(colsum - diag), guarded ----------------
__global__ void k_dinv(const u16* __restrict__ H, const float* __restrict__ partial,
                       float* __restrict__ dinvb){
  const int i = blockIdx.x*256 + threadIdx.x;
  const int c = i >> 11, m = i & (N_-1);
  float s = 0.f;
  #pragma unroll
  for(int p=0;p<16;p++) s += partial[((long)c*16 + p)*N_ + m];
  s -= bf2f(H[c*NN_ + (long)m*N_ + m]);
  dinvb[i] = s > 0.f ? 1.f/s : 0.f;
}

// ---------------- H[j][i] = (j==i) ? 0 : H*dinv[i] ----------------
__global__ void k_colscale(u16* __restrict__ H, const float* __restrict__ dinvb){
  const long i = (long)blockIdx.x*256 + threadIdx.x;
  const int c = blockIdx.y;
  const int j = (int)(i >> 11), ii = (int)(i & (N_-1));
  const long idx = c*NN_ + i;
  const float v = (j==ii) ? 0.f : bf2f(H[idx])*dinvb[c*N_ + ii];
  H[idx] = f2bf(v);
}

// ---------------- dis[c][j] = rsqrt(1 + sum_k HB2t[c][j][k]*mask[k]) ----------------
// Uses colsum(Hn)[k] == (deg[k]>0) exactly (col-normalized), so no H2t pass needed.
__global__ void k_dis(const u16* __restrict__ HB2t, const float* __restrict__ dinvb,
                      float* __restrict__ disv){
  const int c = blockIdx.y, j = blockIdx.x;
  const u16* r = HB2t + (c*(long)N_ + j)*N_;
  const float* dv = dinvb + c*N_;
  float s = 0.f;
  for(int i=threadIdx.x;i<N_;i+=256)
    if(dv[i] > 0.f) s += bf2f(r[i]);
  __shared__ float red[256];
  red[threadIdx.x] = s;
  __syncthreads();
  for(int st=128; st>0; st>>=1){
    if(threadIdx.x < st) red[threadIdx.x] += red[threadIdx.x+st];
    __syncthreads();
  }
  if(threadIdx.x==0){
    const float deg = red[0] + 1.f;
    disv[c*N_ + j] = deg > 0.f ? rsqrtf(deg) : 0.f;
  }
}

// ---------------- 3-in-1 transpose f32 -> bf16 ----------------
__global__ void k_transpose3(const float* __restrict__ gcnW, u16* __restrict__ Wt,
                             const float* __restrict__ lin1W, u16* __restrict__ l1Wt,
                             const float* __restrict__ scoreW, u16* __restrict__ sWt){
  const float* in; u16* out; int R, Cc;
  if(blockIdx.z==0){ in=gcnW;  out=Wt;   R=WIN_;     Cc=WOUT_; }
  else if(blockIdx.z==1){ in=lin1W; out=l1Wt; R=C_*WOUT_; Cc=WOUT_; }
  else { in=scoreW; out=sWt; R=N_; Cc=U_; }
  const int ti = blockIdx.x, tj = blockIdx.y;
  if(ti >= (Cc>>5) || tj >= (R>>5)) return;
  __shared__ float tt[32][33];
  const int x = threadIdx.x, y0 = threadIdx.y;
  #pragma unroll
  for(int i=0;i<4;i++){
    const int y = y0 + i*8;
    tt[y][x] = in[(long)(tj*32+y)*Cc + ti*32 + x];
  }
  __syncthreads();
  #pragma unroll
  for(int i=0;i<4;i++){
    const int y = y0 + i*8;
    out[(long)(ti*32+y)*R + tj*32 + x] = f2bf(tt[x][y]);
  }
}

// ---------------- dual cast f32 -> bf16 (X then Wih) ----------------
__global__ void k_cast2(const float* __restrict__ X, u16* __restrict__ Xbf,
                        const float* __restrict__ Wih, u16* __restrict__ Wihbf){
  const long i = (long)blockIdx.x*256 + threadIdx.x;
  if(i < (long)N_*WIN_) Xbf[i] = f2bf(X[i]);
  else { const long j = i - (long)N_*WIN_; Wihbf[j] = f2bf(Wih[j]); }
}

// ---------------- basket max-pool (grid 52x64; t>=50 writes pad zeros) ----------------
__global__ void k_pool(const float* __restrict__ seqs, const float* __restrict__ X_,
                       u16* __restrict__ bs){
  const int t = blockIdx.x, b = blockIdx.y;
  const int f = threadIdx.x;
  if(t >= T_){
    bs[(long)(BT_ + b*2 + (t-T_))*WOUT_ + f] = 0;
    return;
  }
  const float* mask = seqs + ((long)b*T_ + t)*N_;
  __shared__ int list[N_];
  __shared__ int cnt;
  if(f==0) cnt = 0;
  __syncthreads();
  for(int n0=f; n0<N_; n0+=256){
    if(mask[n0] > 0.f){
      int p = atomicAdd(&cnt, 1);
      list[p] = n0;
    }
  }
  __syncthreads();
  const int m = cnt;
  float mx = -3.4e38f;
  for(int i=0;i<m;i++)
    mx = fmaxf(mx, X_[(long)list[i]*WOUT_ + f]);
  bs[((long)b*T_ + t)*WOUT_ + f] = f2bf(m>0 ? mx : 0.f);
}

// ---------------- pack Whh for register-resident A-frags ----------------
__global__ void k_packWhh3(const float* __restrict__ Whh, u16* __restrict__ P){
  const long idx = (long)blockIdx.x*256 + threadIdx.x;
  const int e  = (int)(idx & 7);
  const int kk = (int)((idx >> 3) & 15);
  const int l  = (int)((idx >> 7) & 63);
  const int w  = (int)((idx >> 13) & 7);
  const int s  = (int)(idx >> 16);
  const int lr = w*16 + (l & 15);
  const int gam = lr & 3, ui = lr >> 2;
  const int grow = gam*512 + s*32 + ui;
  const int k = kk*32 + (l >> 4)*8 + e;
  P[idx] = f2bf(Whh[(long)grow*512 + k]);
}

// ---------------- Hg32 init: buf0 = tag0|h0 (plain layout), buf1 = never-match ----------------
__global__ void k_hinit2(const float* __restrict__ h0, u32* __restrict__ Hg32){
  const int idx = blockIdx.x*256 + threadIdx.x;   // 0..65535
  if(idx < 32768){
    const int b = idx >> 9, u = idx & 511;
    const int grp = b >> 4, bl = b & 15;
    Hg32[grp*16384 + (bl << 9) + u] = (u32)f2bf(h0[idx]);   // tag 0
  } else {
    const int j = idx - 32768;
    const int b = j >> 9, u = j & 511;
    const int grp = b >> 4, bl = b & 15;
    Hg32[grp*16384 + 8192 + (bl << 9) + u] = 0xFFFF0000u;    // tag never matched
  }
}

// ---------------- persistent LSTM v5: poll-on-tagged-data, no barrier ----------------
// Hg32 layout per group: [2 buf][16 bl][512 u] u32 = (tag<<16)|bf16(h)
__global__ __launch_bounds__(512) void k_lstm_all(
    const u16* __restrict__ WhhP, const float* __restrict__ Gq,
    const float* __restrict__ c0v, const int* __restrict__ seqlen,
    u32* __restrict__ Hg32, float* __restrict__ act)
{
  __shared__ u16 Hl[16*512];
  const int tid = threadIdx.x;
  const int w = tid >> 6, l = tid & 63;
  const int grp = blockIdx.x & 3, s = blockIdx.x >> 2;
  const int fr = l & 15, hi = l >> 4;

  bf16x8 wreg[16];
  const u16* wp = WhhP + (((long)s*8 + w)*64 + l)*128;
  #pragma unroll
  for(int kk=0; kk<16; ++kk)
    wreg[kk] = *(const bf16x8*)&wp[kk*8];

  const int ug = s*32 + w*4 + hi;
  const int bl = fr;
  const int bg = grp*16 + bl;
  float cst = c0v[bg*U_ + ug];
  const int sl = seqlen[bg] - 1;
  u32* Hbase = Hg32 + grp*16384;
  const int bl_p = tid >> 5, u0 = (tid & 31) << 4, sw = (bl_p & 7) << 3;
  const int hswz = (bl & 7) << 3;
  const long gqbase = (((long)grp*512 + ug)*16 + bl)*4;
  float4 gq_nxt = *(const float4*)&Gq[gqbase];

  for(int t=0; t<T_; ++t){
    const float4 gq = gq_nxt;
    // ---- stage H_t: poll own 16 tagged words (tag==t), repack into swizzled LDS ----
    const u32* src = Hbase + (t&1)*8192 + tid*16;
    const u32 wt = (u32)t;
    u32 vals[16]; u32 need = 0xFFFFu;
    #pragma unroll
    for(int i=0;i<16;i++){
      u32 v = __hip_atomic_load(&src[i], __ATOMIC_RELAXED, __HIP_MEMORY_SCOPE_AGENT);
      if((v>>16)==wt){ vals[i]=v; need &= ~(1u<<i); }
    }
    while(need){
      #pragma unroll
      for(int i=0;i<16;i++) if(need & (1u<<i)){
        u32 v = __hip_atomic_load(&src[i], __ATOMIC_ACQUIRE, __HIP_MEMORY_SCOPE_AGENT);
        if((v>>16)==wt){ vals[i]=v; need &= ~(1u<<i); }
      }
    }
    uint4 q0, q1;
    q0.x=(vals[0]&0xffffu)|(vals[1]<<16);  q0.y=(vals[2]&0xffffu)|(vals[3]<<16);
    q0.z=(vals[4]&0xffffu)|(vals[5]<<16);  q0.w=(vals[6]&0xffffu)|(vals[7]<<16);
    q1.x=(vals[8]&0xffffu)|(vals[9]<<16);  q1.y=(vals[10]&0xffffu)|(vals[11]<<16);
    q1.z=(vals[12]&0xffffu)|(vals[13]<<16); q1.w=(vals[14]&0xffffu)|(vals[15]<<16);
    *(uint4*)&Hl[(bl_p<<9) + (u0 ^ sw)] = q0;
    *(uint4*)&Hl[(bl_p<<9) + ((u0+8) ^ sw)] = q1;
    __syncthreads();

    // ---- gates: 16 MFMA, W in regs ----
    f32x4 acc = f32x4{0.f,0.f,0.f,0.f};
    #pragma unroll
    for(int kk=0; kk<16; ++kk){
      const int ke = kk*32 + hi*8;
      bf16x8 bb = *(const bf16x8*)&Hl[(bl << 9) + (ke ^ hswz)];
      acc = __builtin_amdgcn_mfma_f32_16x16x32_bf16(wreg[kk], bb, acc, 0, 0, 0);
    }
    if(t+1 < T_)
      gq_nxt = *(const float4*)&Gq[(long)(t+1)*(4*2048*16) + gqbase];

    const float a0 = acc[0] + gq.x;
    const float a1 = acc[1] + gq.y;
    const float a2 = acc[2] + gq.z;
    const float a3 = acc[3] + gq.w;
    const float ig = 1.f/(1.f + expf(-a0));
    const float fg = 1.f/(1.f + expf(-a1));
    const float gg = tanhf(a2);
    const float og = 1.f/(1.f + expf(-a3));
    cst = fg*cst + ig*gg;
    const float h = og*tanhf(cst);
    if(t+1 < T_){
      const u32 hv = (u32)f2bf(h) | ((u32)(t+1) << 16);
      __hip_atomic_store(&Hbase[((t+1)&1)*8192 + (bl << 9) + ug], hv,
                         __ATOMIC_RELAXED, __HIP_MEMORY_SCOPE_AGENT);
    }
    if(sl == t) act[bg*U_ + ug] = h;
    __syncthreads();   // protect Hl from next step's repack until all waves read it
  }
}

// ---------------- out[b][n] = sigmoid(actual[b] . sWt[:,n])  (f32 out) ----------------
__global__ void k_score(const float* __restrict__ actual, const u16* __restrict__ sWt,
                        float* __restrict__ out){
  const int n = blockIdx.x*256 + threadIdx.x;
  const int b = blockIdx.y;
  const float* ab = actual + (long)b*U_;
  float s = 0.f;
  for(int uu=0; uu<U_; uu++) s += ab[uu]*bf2f(sWt[(long)uu*N_ + n]);
  out[(long)b*N_ + n] = 1.f/(1.f + expf(-s));
}

extern "C" void kernel_launch(void* const* d_in, const int* in_sizes, int n_in,
                              void* d_out, int out_size, void* d_ws, size_t ws_size,
                              hipStream_t stream){
  (void)in_sizes; (void)n_in; (void)out_size; (void)ws_size;
  const float* A      = (const float*)d_in[0];
  const float* X      = (const float*)d_in[1];
  const float* seqs   = (const float*)d_in[2];
  const int*   seqlen = (const int*)d_in[3];
  const float* h0     = (const float*)d_in[4];
  const float* c0     = (const float*)d_in[5];
  const float* gtw1   = (const float*)d_in[6];
  const float* gtw2   = (const float*)d_in[7];
  const float* gtw3   = (const float*)d_in[8];
  const float* gcnW   = (const float*)d_in[9];
  const float* gcnB   = (const float*)d_in[10];
  const float* lin1W  = (const float*)d_in[11];
  const float* lin1B  = (const float*)d_in[12];
  const float* Wih    = (const float*)d_in[13];
  const float* Whh    = (const float*)d_in[14];
  const float* bihp   = (const float*)d_in[15];
  const float* bhhp   = (const float*)d_in[16];
  const float* scoreW = (const float*)d_in[17];

  char* ws = (char*)d_ws;
  u16* buf0 = (u16*)(ws + 0);
  u16* buf1 = (u16*)(ws + 16777216);
  u16* buf2 = (u16*)(ws + 33554432);
  char* S0  = ws + 50331648;
  float* filt  = (float*)(S0 + 0);
  float* disv  = (float*)(S0 + 1024);
  u16*  Wt     = (u16*) (S0 + 17408);
  u16*  XWt    = (u16*) (S0 + 148480);
  u16*  catb   = (u16*) (S0 + 1197056);
  u16*  l1Wt   = (u16*) (S0 + 3294208);
  float* Xo    = (float*)(S0 + 3556352);
  u16*  bs     = (u16*) (S0 + 5653504);
  float* act   = (float*)(S0 + 7357440);
  u16*  sWt    = (u16*) (S0 + 7488512);
  u16*  WhhB   = (u16*) (S0 + 9585664);
  u16*  Xbf    = (u16*) (S0 + 11682816);
  u16*  Wihbf  = (u16*) (S0 + 12731392);
  float* bsum  = (float*)(S0 + 13779968);
  float* degp  = (float*)(S0 + 14050304);   // 256 KB
  float* dinvb = (float*)(S0 + 14312448);   // 16 KB
  u32*  Hg32   = (u32*) (S0 + 14328832);    // 256 KB tagged h double-buffer
  u16* HA   = buf0;
  u16* HBt  = buf1;
  u16* Hb   = buf2;
  u16* HB2t = buf0;
  u16* Pd   = buf1;
  float* Gq = (float*)ws;   // 26.2 MiB over buf0+buf1 (dead by then)

  k_prep0<<<dim3(8), 256, 0, stream>>>(gtw1, gtw2, gtw3, filt, bihp, bhhp, bsum);
  k_combineAll<<<dim3(N_/32, N_/32), dim3(32,8), 0, stream>>>(A, filt, HA, HBt);
  k_transpose3<<<dim3(16, 64, 3), dim3(32,8), 0, stream>>>(gcnW, Wt, lin1W, l1Wt, scoreW, sWt);
  k_cast2<<<dim3(4096), 256, 0, stream>>>(X, Xbf, Wih, Wihbf);
  gemm_bt<1><<<dim3(16,16,C_), 256, 0, stream>>>(HA, HBt, Hb, N_, N_, NN_, NN_, NN_, nullptr, 0, nullptr);
  k_degpart<<<dim3(8, 16, C_), 256, 0, stream>>>(Hb, degp);
  k_dinv<<<dim3(16), 256, 0, stream>>>(Hb, degp, dinvb);
  k_colscale<<<dim3(NN_/256, C_), 256, 0, stream>>>(Hb, dinvb);
  k_combineT2<<<dim3(N_/32, N_/32), dim3(32,8), 0, stream>>>(A, filt + 2*C_*E_, HB2t);
  k_dis<<<dim3(N_, C_), 256, 0, stream>>>(HB2t, dinvb, disv);
  // Pd = (HB2t x Hn^T + I) * dis[col]   (k_pd fused into epilogue)
  gemm_bt<5><<<dim3(16,16,C_), 256, 0, stream>>>(HB2t, Hb, Pd, N_, N_, NN_, NN_, NN_, disv, N_, nullptr);
  gemm_bt<1><<<dim3(N_/128, WOUT_/128, 1), 256, 0, stream>>>(Wt, Xbf, XWt, WIN_, N_, 0, 0, 0, nullptr, 0, nullptr);
  gemm_bt<2><<<dim3(WOUT_/128, N_/128, C_), 256, 0, stream>>>(Pd, XWt, catb, N_, C_*WOUT_, NN_, 0, WOUT_, disv, N_, gcnB);
  gemm_bt<3><<<dim3(WOUT_/128, N_/128, 1), 256, 0, stream>>>(catb, l1Wt, Xo, C_*WOUT_, WOUT_, 0, 0, 0, nullptr, 0, lin1B);
  k_pool<<<dim3(52, B_), 256, 0, stream>>>(seqs, Xo, bs);
  gemm_bt<4><<<dim3((4*U_)/128, BTP_/128, 1), 256, 0, stream>>>(bs, Wihbf, Gq, WOUT_, 0, 0, 0, 0, nullptr, 0, bsum);
  k_packWhh3<<<dim3(4096), 256, 0, stream>>>(Whh, WhhB);
  k_hinit2<<<dim3(256), 256, 0, stream>>>(h0, Hg32);
  k_lstm_all<<<dim3(64), 512, 0, stream>>>(WhhB, Gq, c0, seqlen, Hg32, act);
  k_score<<<dim3(N_/256, B_), 256, 0, stream>>>(act, sWt, (float*)d_out);
}

// Round 10
// 767.000 us; speedup vs baseline: 4.3528x; 4.3528x over previous
//
#include <hip/hip_runtime.h>
#include <stdint.h>

#define E_ 3
#define C_ 2
#define N_ 2048
#define B_ 64
#define T_ 50
#define WIN_ 256
#define WOUT_ 256
#define U_ 512
#define BT_ (B_*T_)
#define BTP_ 3328

typedef unsigned short u16;
typedef unsigned int u32;
typedef __bf16 bf16x8 __attribute__((ext_vector_type(8)));
typedef float f32x4 __attribute__((ext_vector_type(4)));

#define NN_ (2048LL*2048LL)

__device__ __forceinline__ float bf2f(u16 u){
  u32 x = ((u32)u) << 16; return __builtin_bit_cast(float, x);
}
__device__ __forceinline__ u16 f2bf(float f){
  u32 x = __builtin_bit_cast(u32, f);
  u32 r = (x + 0x7fffu + ((x >> 16) & 1u)) >> 16;
  return (u16)r;
}

__device__ __forceinline__ void gload16(const u16* g, u16* l){
  __builtin_amdgcn_global_load_lds((const __attribute__((address_space(1))) u32*)g,
                                   (__attribute__((address_space(3))) u32*)l, 16, 0, 0);
}

// ---------------- prep0: softmax filters + bsum ----------------
__global__ void k_prep0(const float* __restrict__ w1, const float* __restrict__ w2,
                        const float* __restrict__ w3, float* __restrict__ filt,
                        const float* __restrict__ bih, const float* __restrict__ bhh,
                        float* __restrict__ bsum){
  const int i = blockIdx.x*256 + threadIdx.x;
  bsum[i] = bih[i] + bhh[i];
  if(blockIdx.x==0 && threadIdx.x < 3*C_){
    const int t = threadIdx.x;
    const int fi = t / C_, c = t % C_;
    const float* w = (fi==0) ? w1 : ((fi==1) ? w2 : w3);
    float v[E_]; float mx = -3.4e38f;
    for(int e=0;e<E_;e++){ v[e] = w[c*E_+e]; mx = fmaxf(mx, v[e]); }
    float s = 0.f;
    for(int e=0;e<E_;e++){ v[e] = expf(v[e]-mx); s += v[e]; }
    for(int e=0;e<E_;e++) filt[(fi*C_+c)*E_ + e] = v[e]/s;
  }
}

// ---------------- fused combine: HA (direct) + HBt (transposed), A read ONCE ----------------
__global__ void k_combineAll(const float* __restrict__ A, const float* __restrict__ filt,
                             u16* __restrict__ HA, u16* __restrict__ HBt){
  __shared__ float te[3][32][33];
  const int ti = blockIdx.x, tj = blockIdx.y;
  const int x = threadIdx.x, y0 = threadIdx.y;
  #pragma unroll
  for(int i=0;i<4;i++){
    const int y = y0 + i*8;
    const long base = (long)(tj*32+y)*N_ + ti*32 + x;
    const float a0 = A[0*NN_+base], a1 = A[1*NN_+base], a2 = A[2*NN_+base];
    te[0][y][x]=a0; te[1][y][x]=a1; te[2][y][x]=a2;
    #pragma unroll
    for(int c=0;c<C_;c++)
      HA[c*NN_ + base] = f2bf(filt[c*E_]*a0 + filt[c*E_+1]*a1 + filt[c*E_+2]*a2);
  }
  __syncthreads();
  #pragma unroll
  for(int i=0;i<4;i++){
    const int y = y0 + i*8;
    const long ob = (long)(ti*32+y)*N_ + tj*32 + x;
    const float a0=te[0][x][y], a1=te[1][x][y], a2=te[2][x][y];
    #pragma unroll
    for(int c=0;c<C_;c++)
      HBt[c*NN_+ob] = f2bf(filt[(C_+c)*E_]*a0 + filt[(C_+c)*E_+1]*a1 + filt[(C_+c)*E_+2]*a2);
  }
}

// ---------------- HB2t both channels, one pass over A ----------------
__global__ void k_combineT2(const float* __restrict__ A, const float* __restrict__ f,
                            u16* __restrict__ outp){
  __shared__ float te[3][32][33];
  const int ti = blockIdx.x, tj = blockIdx.y;
  const int x = threadIdx.x, y0 = threadIdx.y;
  #pragma unroll
  for(int i=0;i<4;i++){
    const int y = y0 + i*8;
    const long base = (long)(tj*32+y)*N_ + ti*32 + x;
    te[0][y][x]=A[0*NN_+base]; te[1][y][x]=A[1*NN_+base]; te[2][y][x]=A[2*NN_+base];
  }
  __syncthreads();
  #pragma unroll
  for(int i=0;i<4;i++){
    const int y = y0 + i*8;
    const long ob = (long)(ti*32+y)*N_ + tj*32 + x;
    const float a0=te[0][x][y], a1=te[1][x][y], a2=te[2][x][y];
    #pragma unroll
    for(int c=0;c<C_;c++)
      outp[c*NN_+ob] = f2bf(f[c*E_]*a0 + f[c*E_+1]*a1 + f[c*E_+2]*a2);
  }
}

// ---------------- MFMA GEMM: OUT[i][j] = sum_k A[i][k]*B[j][k] ----------------
// MODE 1: bf16 raw; 2: bf16 relu(dis[row]*acc+bias[col]); 3: f32 acc+bias[col];
// MODE 4: Gq scatter; MODE 5: bf16 (acc + (row==col)) * disv[col]  (fused Pd)
template<int MODE>
__global__ __launch_bounds__(256) void gemm_bt(
    const u16* __restrict__ Ag, const u16* __restrict__ Bg, void* __restrict__ Cg,
    int K, int ldc, long sA, long sB, long sC,
    const float* __restrict__ disv, int sDis, const float* __restrict__ bias)
{
  __shared__ u16 At[128*32];
  __shared__ u16 Bt[128*32];
  const int tid = threadIdx.x;
  const int w = tid >> 6, l = tid & 63;
  const int z = blockIdx.z;
  const u16* Ab = Ag + (long)z*sA;
  const u16* Bb = Bg + (long)z*sB;
  const int rowBase = blockIdx.y*128;
  const int colBase = blockIdx.x*128;

  f32x4 acc[4][4];
  #pragma unroll
  for(int i=0;i<4;i++)
    #pragma unroll
    for(int j=0;j<4;j++)
      acc[i][j] = f32x4{0.f,0.f,0.f,0.f};

  const int wr = w >> 1, wc = w & 1;
  const int arow0 = (w*2+0)*16 + (l>>2);
  const int arow1 = (w*2+1)*16 + (l>>2);
  const int kc = (((l&3) ^ ((l>>2)&3)))*8;
  const int frow = l & 15;
  const int fkc = l >> 4;

  const int nk = K >> 5;
  for(int kt=0; kt<nk; ++kt){
    const int k0 = kt << 5;
    gload16(Ab + (long)(rowBase+arow0)*K + k0 + kc, &At[(w*2+0)*512]);
    gload16(Ab + (long)(rowBase+arow1)*K + k0 + kc, &At[(w*2+1)*512]);
    gload16(Bb + (long)(colBase+arow0)*K + k0 + kc, &Bt[(w*2+0)*512]);
    gload16(Bb + (long)(colBase+arow1)*K + k0 + kc, &Bt[(w*2+1)*512]);
    __syncthreads();
    bf16x8 af[4], bfv[4];
    #pragma unroll
    for(int m=0;m<4;m++){
      const int rr = wr*64 + m*16 + frow;
      af[m] = *(const bf16x8*)&At[rr*32 + ((fkc ^ (rr&3))<<3)];
    }
    #pragma unroll
    for(int n=0;n<4;n++){
      const int rr = wc*64 + n*16 + frow;
      bfv[n] = *(const bf16x8*)&Bt[rr*32 + ((fkc ^ (rr&3))<<3)];
    }
    #pragma unroll
    for(int m=0;m<4;m++)
      #pragma unroll
      for(int n=0;n<4;n++)
        acc[m][n] = __builtin_amdgcn_mfma_f32_16x16x32_bf16(af[m], bfv[n], acc[m][n], 0, 0, 0);
    __syncthreads();
  }

  #pragma unroll
  for(int m=0;m<4;m++){
    const int row0 = rowBase + wr*64 + m*16 + (l>>4)*4;
    #pragma unroll
    for(int n=0;n<4;n++){
      const int col = colBase + wc*64 + n*16 + (l&15);
      #pragma unroll
      for(int r=0;r<4;r++){
        const float v = acc[m][n][r];
        if(MODE==1){
          ((u16*)Cg)[z*sC + (long)(row0+r)*ldc + col] = f2bf(v);
        } else if(MODE==2){
          float o = disv[z*(long)sDis + row0 + r]*v + bias[col];
          o = o > 0.f ? o : 0.f;
          ((u16*)Cg)[z*sC + (long)(row0+r)*ldc + col] = f2bf(o);
        } else if(MODE==3){
          ((float*)Cg)[z*sC + (long)(row0+r)*ldc + col] = v + bias[col];
        } else if(MODE==4){
          const int row = row0 + r;
          if(row < BT_){
            const int bb = row/50, tt = row - bb*50;
            const int gq = col >> 9, ugg = col & 511;
            ((float*)Cg)[((((long)tt*4 + (bb>>4))*512 + ugg)*16 + (bb&15))*4 + gq] = v + bias[col];
          }
        } else if(MODE==5){
          const int row = row0 + r;
          const float o = (v + (row==col ? 1.f : 0.f)) * disv[z*(long)sDis + col];
          ((u16*)Cg)[z*sC + (long)row*ldc + col] = f2bf(o);
        }
      }
    }
  }
}

// ---------------- column-degree partial sums ----------------
__global__ void k_degpart(const u16* __restrict__ H, float* __restrict__ partial){
  const int c = blockIdx.z;
  const int col = blockIdx.x*256 + threadIdx.x;
  const int r0 = blockIdx.y*128;
  const u16* Hc = H + c*NN_;
  float s = 0.f;
  #pragma unroll 4
  for(int r=0;r<128;r++) s += bf2f(Hc[(long)(r0+r)*N_ + col]);
  partial[((long)c*16 + blockIdx.y)*N_ + col] = s;
}

// ---------------- dinv[c][m] = 1/(colsum - diag), guarded ----------------
__global__ void k_dinv(const u16* __restrict__ H, const float* __restrict__ partial,
                       float* __restrict__ dinvb){
  const int i = blockIdx.x*256 + threadIdx.x;
  const int c = i >> 11, m = i & (N_-1);
  float s = 0.f;
  #pragma unroll
  for(int p=0;p<16;p++) s += partial[((long)c*16 + p)*N_ + m];
  s -= bf2f(H[c*NN_ + (long)m*N_ + m]);
  dinvb[i] = s > 0.f ? 1.f/s : 0.f;
}

// ---------------- H[j][i] = (j==i) ? 0 : H*dinv[i] ----------------
__global__ void k_colscale(u16* __restrict__ H, const float* __restrict__ dinvb){
  const long i = (long)blockIdx.x*256 + threadIdx.x;
  const int c = blockIdx.y;
  const int j = (int)(i >> 11), ii = (int)(i & (N_-1));
  const long idx = c*NN_ + i;
  const float v = (j==ii) ? 0.f : bf2f(H[idx])*dinvb[c*N_ + ii];
  H[idx] = f2bf(v);
}

// ---------------- dis[c][j] = rsqrt(1 + sum_k HB2t[c][j][k]*mask[k]) ----------------
__global__ void k_dis(const u16* __restrict__ HB2t, const float* __restrict__ dinvb,
                      float* __restrict__ disv){
  const int c = blockIdx.y, j = blockIdx.x;
  const u16* r = HB2t + (c*(long)N_ + j)*N_;
  const float* dv = dinvb + c*N_;
  float s = 0.f;
  for(int i=threadIdx.x;i<N_;i+=256)
    if(dv[i] > 0.f) s += bf2f(r[i]);
  __shared__ float red[256];
  red[threadIdx.x] = s;
  __syncthreads();
  for(int st=128; st>0; st>>=1){
    if(threadIdx.x < st) red[threadIdx.x] += red[threadIdx.x+st];
    __syncthreads();
  }
  if(threadIdx.x==0){
    const float deg = red[0] + 1.f;
    disv[c*N_ + j] = deg > 0.f ? rsqrtf(deg) : 0.f;
  }
}

// ---------------- 3-in-1 transpose f32 -> bf16 ----------------
__global__ void k_transpose3(const float* __restrict__ gcnW, u16* __restrict__ Wt,
                             const float* __restrict__ lin1W, u16* __restrict__ l1Wt,
                             const float* __restrict__ scoreW, u16* __restrict__ sWt){
  const float* in; u16* out; int R, Cc;
  if(blockIdx.z==0){ in=gcnW;  out=Wt;   R=WIN_;     Cc=WOUT_; }
  else if(blockIdx.z==1){ in=lin1W; out=l1Wt; R=C_*WOUT_; Cc=WOUT_; }
  else { in=scoreW; out=sWt; R=N_; Cc=U_; }
  const int ti = blockIdx.x, tj = blockIdx.y;
  if(ti >= (Cc>>5) || tj >= (R>>5)) return;
  __shared__ float tt[32][33];
  const int x = threadIdx.x, y0 = threadIdx.y;
  #pragma unroll
  for(int i=0;i<4;i++){
    const int y = y0 + i*8;
    tt[y][x] = in[(long)(tj*32+y)*Cc + ti*32 + x];
  }
  __syncthreads();
  #pragma unroll
  for(int i=0;i<4;i++){
    const int y = y0 + i*8;
    out[(long)(ti*32+y)*R + tj*32 + x] = f2bf(tt[x][y]);
  }
}

// ---------------- dual cast f32 -> bf16 (X then Wih) ----------------
__global__ void k_cast2(const float* __restrict__ X, u16* __restrict__ Xbf,
                        const float* __restrict__ Wih, u16* __restrict__ Wihbf){
  const long i = (long)blockIdx.x*256 + threadIdx.x;
  if(i < (long)N_*WIN_) Xbf[i] = f2bf(X[i]);
  else { const long j = i - (long)N_*WIN_; Wihbf[j] = f2bf(Wih[j]); }
}

// ---------------- basket max-pool (grid 52x64; t>=50 writes pad zeros) ----------------
__global__ void k_pool(const float* __restrict__ seqs, const float* __restrict__ X_,
                       u16* __restrict__ bs){
  const int t = blockIdx.x, b = blockIdx.y;
  const int f = threadIdx.x;
  if(t >= T_){
    bs[(long)(BT_ + b*2 + (t-T_))*WOUT_ + f] = 0;
    return;
  }
  const float* mask = seqs + ((long)b*T_ + t)*N_;
  __shared__ int list[N_];
  __shared__ int cnt;
  if(f==0) cnt = 0;
  __syncthreads();
  for(int n0=f; n0<N_; n0+=256){
    if(mask[n0] > 0.f){
      int p = atomicAdd(&cnt, 1);
      list[p] = n0;
    }
  }
  __syncthreads();
  const int m = cnt;
  float mx = -3.4e38f;
  for(int i=0;i<m;i++)
    mx = fmaxf(mx, X_[(long)list[i]*WOUT_ + f]);
  bs[((long)b*T_ + t)*WOUT_ + f] = f2bf(m>0 ? mx : 0.f);
}

// ---------------- pack Whh for register-resident A-frags ----------------
__global__ void k_packWhh3(const float* __restrict__ Whh, u16* __restrict__ P){
  const long idx = (long)blockIdx.x*256 + threadIdx.x;
  const int e  = (int)(idx & 7);
  const int kk = (int)((idx >> 3) & 15);
  const int l  = (int)((idx >> 7) & 63);
  const int w  = (int)((idx >> 13) & 7);
  const int s  = (int)(idx >> 16);
  const int lr = w*16 + (l & 15);
  const int gam = lr & 3, ui = lr >> 2;
  const int grow = gam*512 + s*32 + ui;
  const int k = kk*32 + (l >> 4)*8 + e;
  P[idx] = f2bf(Whh[(long)grow*512 + k]);
}

// ---------------- Hg32 init: buf0 = tag0|h0 (plain layout), buf1 = never-match ----------------
__global__ void k_hinit2(const float* __restrict__ h0, u32* __restrict__ Hg32){
  const int idx = blockIdx.x*256 + threadIdx.x;   // 0..65535
  if(idx < 32768){
    const int b = idx >> 9, u = idx & 511;
    const int grp = b >> 4, bl = b & 15;
    Hg32[grp*16384 + (bl << 9) + u] = (u32)f2bf(h0[idx]);   // tag 0
  } else {
    const int j = idx - 32768;
    const int b = j >> 9, u = j & 511;
    const int grp = b >> 4, bl = b & 15;
    Hg32[grp*16384 + 8192 + (bl << 9) + u] = 0xFFFF0000u;    // tag never matched
  }
}

// ---------------- persistent LSTM v6: tagged-data poll at SYSTEM scope (LLC, no inv) ----------------
// Hg32 layout per group: [2 buf][16 bl][512 u] u32 = (tag<<16)|bf16(h)
__global__ __launch_bounds__(512) void k_lstm_all(
    const u16* __restrict__ WhhP, const float* __restrict__ Gq,
    const float* __restrict__ c0v, const int* __restrict__ seqlen,
    u32* __restrict__ Hg32, float* __restrict__ act)
{
  __shared__ u16 Hl[16*512];
  const int tid = threadIdx.x;
  const int w = tid >> 6, l = tid & 63;
  const int grp = blockIdx.x & 3, s = blockIdx.x >> 2;
  const int fr = l & 15, hi = l >> 4;

  bf16x8 wreg[16];
  const u16* wp = WhhP + (((long)s*8 + w)*64 + l)*128;
  #pragma unroll
  for(int kk=0; kk<16; ++kk)
    wreg[kk] = *(const bf16x8*)&wp[kk*8];

  const int ug = s*32 + w*4 + hi;
  const int bl = fr;
  const int bg = grp*16 + bl;
  float cst = c0v[bg*U_ + ug];
  const int sl = seqlen[bg] - 1;
  u32* Hbase = Hg32 + grp*16384;
  const int bl_p = tid >> 5, u0 = (tid & 31) << 4, sw = (bl_p & 7) << 3;
  const int hswz = (bl & 7) << 3;
  const long gqbase = (((long)grp*512 + ug)*16 + bl)*4;
  float4 gq_nxt = *(const float4*)&Gq[gqbase];

  for(int t=0; t<T_; ++t){
    const float4 gq = gq_nxt;
    // ---- stage H_t: poll own 16 tagged words (tag==t) at SYSTEM scope ----
    // Relaxed system-scope loads bypass L2 (sc1) -> read the coherent LLC; no
    // invalidates needed. Fallback: if a sweep doesn't finish, ONE acquire load
    // refreshes caches (bounds staleness even if relaxed doesn't bypass).
    const u32* src = Hbase + (t&1)*8192 + tid*16;
    const u32 wt = (u32)t;
    u32 vals[16]; u32 need = 0xFFFFu;
    while(need){
      #pragma unroll
      for(int i=0;i<16;i++) if(need & (1u<<i)){
        u32 v = __hip_atomic_load(&src[i], __ATOMIC_RELAXED, __HIP_MEMORY_SCOPE_SYSTEM);
        if((v>>16)==wt){ vals[i]=v; need &= ~(1u<<i); }
      }
      if(need){
        // one acquire (cache-refresh) per failed sweep, then retry relaxed
        const int fi = 31 - __builtin_clz(need);
        u32 v = __hip_atomic_load(&src[fi], __ATOMIC_ACQUIRE, __HIP_MEMORY_SCOPE_SYSTEM);
        if((v>>16)==wt){ vals[fi]=v; need &= ~(1u<<fi); }
      }
    }
    uint4 q0, q1;
    q0.x=(vals[0]&0xffffu)|(vals[1]<<16);  q0.y=(vals[2]&0xffffu)|(vals[3]<<16);
    q0.z=(vals[4]&0xffffu)|(vals[5]<<16);  q0.w=(vals[6]&0xffffu)|(vals[7]<<16);
    q1.x=(vals[8]&0xffffu)|(vals[9]<<16);  q1.y=(vals[10]&0xffffu)|(vals[11]<<16);
    q1.z=(vals[12]&0xffffu)|(vals[13]<<16); q1.w=(vals[14]&0xffffu)|(vals[15]<<16);
    *(uint4*)&Hl[(bl_p<<9) + (u0 ^ sw)] = q0;
    *(uint4*)&Hl[(bl_p<<9) + ((u0+8) ^ sw)] = q1;
    __syncthreads();

    // ---- gates: 16 MFMA, W in regs ----
    f32x4 acc = f32x4{0.f,0.f,0.f,0.f};
    #pragma unroll
    for(int kk=0; kk<16; ++kk){
      const int ke = kk*32 + hi*8;
      bf16x8 bb = *(const bf16x8*)&Hl[(bl << 9) + (ke ^ hswz)];
      acc = __builtin_amdgcn_mfma_f32_16x16x32_bf16(wreg[kk], bb, acc, 0, 0, 0);
    }
    if(t+1 < T_)
      gq_nxt = *(const float4*)&Gq[(long)(t+1)*(4*2048*16) + gqbase];

    const float a0 = acc[0] + gq.x;
    const float a1 = acc[1] + gq.y;
    const float a2 = acc[2] + gq.z;
    const float a3 = acc[3] + gq.w;
    const float ig = 1.f/(1.f + expf(-a0));
    const float fg = 1.f/(1.f + expf(-a1));
    const float gg = tanhf(a2);
    const float og = 1.f/(1.f + expf(-a3));
    cst = fg*cst + ig*gg;
    const float h = og*tanhf(cst);
    if(t+1 < T_){
      const u32 hv = (u32)f2bf(h) | ((u32)(t+1) << 16);
      // system-scope store: writes through (sc1) to the LLC, visible to all XCDs
      __hip_atomic_store(&Hbase[((t+1)&1)*8192 + (bl << 9) + ug], hv,
                         __ATOMIC_RELAXED, __HIP_MEMORY_SCOPE_SYSTEM);
    }
    if(sl == t) act[bg*U_ + ug] = h;
    __syncthreads();   // protect Hl from next step's repack until all waves read it
  }
}

// ---------------- out[b][n] = sigmoid(actual[b] . sWt[:,n])  (f32 out) ----------------
__global__ void k_score(const float* __restrict__ actual, const u16* __restrict__ sWt,
                        float* __restrict__ out){
  const int n = blockIdx.x*256 + threadIdx.x;
  const int b = blockIdx.y;
  const float* ab = actual + (long)b*U_;
  float s = 0.f;
  for(int uu=0; uu<U_; uu++) s += ab[uu]*bf2f(sWt[(long)uu*N_ + n]);
  out[(long)b*N_ + n] = 1.f/(1.f + expf(-s));
}

extern "C" void kernel_launch(void* const* d_in, const int* in_sizes, int n_in,
                              void* d_out, int out_size, void* d_ws, size_t ws_size,
                              hipStream_t stream){
  (void)in_sizes; (void)n_in; (void)out_size; (void)ws_size;
  const float* A      = (const float*)d_in[0];
  const float* X      = (const float*)d_in[1];
  const float* seqs   = (const float*)d_in[2];
  const int*   seqlen = (const int*)d_in[3];
  const float* h0     = (const float*)d_in[4];
  const float* c0     = (const float*)d_in[5];
  const float* gtw1   = (const float*)d_in[6];
  const float* gtw2   = (const float*)d_in[7];
  const float* gtw3   = (const float*)d_in[8];
  const float* gcnW   = (const float*)d_in[9];
  const float* gcnB   = (const float*)d_in[10];
  const float* lin1W  = (const float*)d_in[11];
  const float* lin1B  = (const float*)d_in[12];
  const float* Wih    = (const float*)d_in[13];
  const float* Whh    = (const float*)d_in[14];
  const float* bihp   = (const float*)d_in[15];
  const float* bhhp   = (const float*)d_in[16];
  const float* scoreW = (const float*)d_in[17];

  char* ws = (char*)d_ws;
  u16* buf0 = (u16*)(ws + 0);
  u16* buf1 = (u16*)(ws + 16777216);
  u16* buf2 = (u16*)(ws + 33554432);
  char* S0  = ws + 50331648;
  float* filt  = (float*)(S0 + 0);
  float* disv  = (float*)(S0 + 1024);
  u16*  Wt     = (u16*) (S0 + 17408);
  u16*  XWt    = (u16*) (S0 + 148480);
  u16*  catb   = (u16*) (S0 + 1197056);
  u16*  l1Wt   = (u16*) (S0 + 3294208);
  float* Xo    = (float*)(S0 + 3556352);
  u16*  bs     = (u16*) (S0 + 5653504);
  float* act   = (float*)(S0 + 7357440);
  u16*  sWt    = (u16*) (S0 + 7488512);
  u16*  WhhB   = (u16*) (S0 + 9585664);
  u16*  Xbf    = (u16*) (S0 + 11682816);
  u16*  Wihbf  = (u16*) (S0 + 12731392);
  float* bsum  = (float*)(S0 + 13779968);
  float* degp  = (float*)(S0 + 14050304);
  float* dinvb = (float*)(S0 + 14312448);
  u32*  Hg32   = (u32*) (S0 + 14328832);
  u16* HA   = buf0;
  u16* HBt  = buf1;
  u16* Hb   = buf2;
  u16* HB2t = buf0;
  u16* Pd   = buf1;
  float* Gq = (float*)ws;

  k_prep0<<<dim3(8), 256, 0, stream>>>(gtw1, gtw2, gtw3, filt, bihp, bhhp, bsum);
  k_combineAll<<<dim3(N_/32, N_/32), dim3(32,8), 0, stream>>>(A, filt, HA, HBt);
  k_transpose3<<<dim3(16, 64, 3), dim3(32,8), 0, stream>>>(gcnW, Wt, lin1W, l1Wt, scoreW, sWt);
  k_cast2<<<dim3(4096), 256, 0, stream>>>(X, Xbf, Wih, Wihbf);
  gemm_bt<1><<<dim3(16,16,C_), 256, 0, stream>>>(HA, HBt, Hb, N_, N_, NN_, NN_, NN_, nullptr, 0, nullptr);
  k_degpart<<<dim3(8, 16, C_), 256, 0, stream>>>(Hb, degp);
  k_dinv<<<dim3(16), 256, 0, stream>>>(Hb, degp, dinvb);
  k_colscale<<<dim3(NN_/256, C_), 256, 0, stream>>>(Hb, dinvb);
  k_combineT2<<<dim3(N_/32, N_/32), dim3(32,8), 0, stream>>>(A, filt + 2*C_*E_, HB2t);
  k_dis<<<dim3(N_, C_), 256, 0, stream>>>(HB2t, dinvb, disv);
  gemm_bt<5><<<dim3(16,16,C_), 256, 0, stream>>>(HB2t, Hb, Pd, N_, N_, NN_, NN_, NN_, disv, N_, nullptr);
  gemm_bt<1><<<dim3(N_/128, WOUT_/128, 1), 256, 0, stream>>>(Wt, Xbf, XWt, WIN_, N_, 0, 0, 0, nullptr, 0, nullptr);
  gemm_bt<2><<<dim3(WOUT_/128, N_/128, C_), 256, 0, stream>>>(Pd, XWt, catb, N_, C_*WOUT_, NN_, 0, WOUT_, disv, N_, gcnB);
  gemm_bt<3><<<dim3(WOUT_/128, N_/128, 1), 256, 0, stream>>>(catb, l1Wt, Xo, C_*WOUT_, WOUT_, 0, 0, 0, nullptr, 0, lin1B);
  k_pool<<<dim3(52, B_), 256, 0, stream>>>(seqs, Xo, bs);
  gemm_bt<4><<<dim3((4*U_)/128, BTP_/128, 1), 256, 0, stream>>>(bs, Wihbf, Gq, WOUT_, 0, 0, 0, 0, nullptr, 0, bsum);
  k_packWhh3<<<dim3(4096), 256, 0, stream>>>(Whh, WhhB);
  k_hinit2<<<dim3(256), 256, 0, stream>>>(h0, Hg32);
  k_lstm_all<<<dim3(64), 512, 0, stream>>>(WhhB, Gq, c0, seqlen, Hg32, act);
  k_score<<<dim3(N_/256, B_), 256, 0, stream>>>(act, sWt, (float*)d_out);
}

// Round 11
// 690.478 us; speedup vs baseline: 4.8352x; 1.1108x over previous
//
#include <hip/hip_runtime.h>
#include <stdint.h>

#define E_ 3
#define C_ 2
#define N_ 2048
#define B_ 64
#define T_ 50
#define WIN_ 256
#define WOUT_ 256
#define U_ 512
#define BT_ (B_*T_)
#define BTP_ 3328

typedef unsigned short u16;
typedef unsigned int u32;
typedef __bf16 bf16x8 __attribute__((ext_vector_type(8)));
typedef float f32x4 __attribute__((ext_vector_type(4)));

#define NN_ (2048LL*2048LL)

__device__ __forceinline__ float bf2f(u16 u){
  u32 x = ((u32)u) << 16; return __builtin_bit_cast(float, x);
}
__device__ __forceinline__ u16 f2bf(float f){
  u32 x = __builtin_bit_cast(u32, f);
  u32 r = (x + 0x7fffu + ((x >> 16) & 1u)) >> 16;
  return (u16)r;
}

__device__ __forceinline__ void gload16(const u16* g, u16* l){
  __builtin_amdgcn_global_load_lds((const __attribute__((address_space(1))) u32*)g,
                                   (__attribute__((address_space(3))) u32*)l, 16, 0, 0);
}

// ---------------- prep0: softmax filters + bsum ----------------
__global__ void k_prep0(const float* __restrict__ w1, const float* __restrict__ w2,
                        const float* __restrict__ w3, float* __restrict__ filt,
                        const float* __restrict__ bih, const float* __restrict__ bhh,
                        float* __restrict__ bsum){
  const int i = blockIdx.x*256 + threadIdx.x;
  bsum[i] = bih[i] + bhh[i];
  if(blockIdx.x==0 && threadIdx.x < 3*C_){
    const int t = threadIdx.x;
    const int fi = t / C_, c = t % C_;
    const float* w = (fi==0) ? w1 : ((fi==1) ? w2 : w3);
    float v[E_]; float mx = -3.4e38f;
    for(int e=0;e<E_;e++){ v[e] = w[c*E_+e]; mx = fmaxf(mx, v[e]); }
    float s = 0.f;
    for(int e=0;e<E_;e++){ v[e] = expf(v[e]-mx); s += v[e]; }
    for(int e=0;e<E_;e++) filt[(fi*C_+c)*E_ + e] = v[e]/s;
  }
}

// ---------------- fused combine: HA (direct) + HBt (transposed), A read ONCE ----------------
__global__ void k_combineAll(const float* __restrict__ A, const float* __restrict__ filt,
                             u16* __restrict__ HA, u16* __restrict__ HBt){
  __shared__ float te[3][32][33];
  const int ti = blockIdx.x, tj = blockIdx.y;
  const int x = threadIdx.x, y0 = threadIdx.y;
  #pragma unroll
  for(int i=0;i<4;i++){
    const int y = y0 + i*8;
    const long base = (long)(tj*32+y)*N_ + ti*32 + x;
    const float a0 = A[0*NN_+base], a1 = A[1*NN_+base], a2 = A[2*NN_+base];
    te[0][y][x]=a0; te[1][y][x]=a1; te[2][y][x]=a2;
    #pragma unroll
    for(int c=0;c<C_;c++)
      HA[c*NN_ + base] = f2bf(filt[c*E_]*a0 + filt[c*E_+1]*a1 + filt[c*E_+2]*a2);
  }
  __syncthreads();
  #pragma unroll
  for(int i=0;i<4;i++){
    const int y = y0 + i*8;
    const long ob = (long)(ti*32+y)*N_ + tj*32 + x;
    const float a0=te[0][x][y], a1=te[1][x][y], a2=te[2][x][y];
    #pragma unroll
    for(int c=0;c<C_;c++)
      HBt[c*NN_+ob] = f2bf(filt[(C_+c)*E_]*a0 + filt[(C_+c)*E_+1]*a1 + filt[(C_+c)*E_+2]*a2);
  }
}

// ---------------- HB2t both channels, one pass over A ----------------
__global__ void k_combineT2(const float* __restrict__ A, const float* __restrict__ f,
                            u16* __restrict__ outp){
  __shared__ float te[3][32][33];
  const int ti = blockIdx.x, tj = blockIdx.y;
  const int x = threadIdx.x, y0 = threadIdx.y;
  #pragma unroll
  for(int i=0;i<4;i++){
    const int y = y0 + i*8;
    const long base = (long)(tj*32+y)*N_ + ti*32 + x;
    te[0][y][x]=A[0*NN_+base]; te[1][y][x]=A[1*NN_+base]; te[2][y][x]=A[2*NN_+base];
  }
  __syncthreads();
  #pragma unroll
  for(int i=0;i<4;i++){
    const int y = y0 + i*8;
    const long ob = (long)(ti*32+y)*N_ + tj*32 + x;
    const float a0=te[0][x][y], a1=te[1][x][y], a2=te[2][x][y];
    #pragma unroll
    for(int c=0;c<C_;c++)
      outp[c*NN_+ob] = f2bf(f[c*E_]*a0 + f[c*E_+1]*a1 + f[c*E_+2]*a2);
  }
}

// ---------------- MFMA GEMM: OUT[i][j] = sum_k A[i][k]*B[j][k] ----------------
// MODE 1: bf16 raw; 2: bf16 relu(dis[row]*acc+bias[col]); 3: f32 acc+bias[col];
// MODE 4: Gq scatter (8-batch groups); MODE 5: bf16 (acc + (row==col)) * disv[col]
template<int MODE>
__global__ __launch_bounds__(256) void gemm_bt(
    const u16* __restrict__ Ag, const u16* __restrict__ Bg, void* __restrict__ Cg,
    int K, int ldc, long sA, long sB, long sC,
    const float* __restrict__ disv, int sDis, const float* __restrict__ bias)
{
  __shared__ u16 At[128*32];
  __shared__ u16 Bt[128*32];
  const int tid = threadIdx.x;
  const int w = tid >> 6, l = tid & 63;
  const int z = blockIdx.z;
  const u16* Ab = Ag + (long)z*sA;
  const u16* Bb = Bg + (long)z*sB;
  const int rowBase = blockIdx.y*128;
  const int colBase = blockIdx.x*128;

  f32x4 acc[4][4];
  #pragma unroll
  for(int i=0;i<4;i++)
    #pragma unroll
    for(int j=0;j<4;j++)
      acc[i][j] = f32x4{0.f,0.f,0.f,0.f};

  const int wr = w >> 1, wc = w & 1;
  const int arow0 = (w*2+0)*16 + (l>>2);
  const int arow1 = (w*2+1)*16 + (l>>2);
  const int kc = (((l&3) ^ ((l>>2)&3)))*8;
  const int frow = l & 15;
  const int fkc = l >> 4;

  const int nk = K >> 5;
  for(int kt=0; kt<nk; ++kt){
    const int k0 = kt << 5;
    gload16(Ab + (long)(rowBase+arow0)*K + k0 + kc, &At[(w*2+0)*512]);
    gload16(Ab + (long)(rowBase+arow1)*K + k0 + kc, &At[(w*2+1)*512]);
    gload16(Bb + (long)(colBase+arow0)*K + k0 + kc, &Bt[(w*2+0)*512]);
    gload16(Bb + (long)(colBase+arow1)*K + k0 + kc, &Bt[(w*2+1)*512]);
    __syncthreads();
    bf16x8 af[4], bfv[4];
    #pragma unroll
    for(int m=0;m<4;m++){
      const int rr = wr*64 + m*16 + frow;
      af[m] = *(const bf16x8*)&At[rr*32 + ((fkc ^ (rr&3))<<3)];
    }
    #pragma unroll
    for(int n=0;n<4;n++){
      const int rr = wc*64 + n*16 + frow;
      bfv[n] = *(const bf16x8*)&Bt[rr*32 + ((fkc ^ (rr&3))<<3)];
    }
    #pragma unroll
    for(int m=0;m<4;m++)
      #pragma unroll
      for(int n=0;n<4;n++)
        acc[m][n] = __builtin_amdgcn_mfma_f32_16x16x32_bf16(af[m], bfv[n], acc[m][n], 0, 0, 0);
    __syncthreads();
  }

  #pragma unroll
  for(int m=0;m<4;m++){
    const int row0 = rowBase + wr*64 + m*16 + (l>>4)*4;
    #pragma unroll
    for(int n=0;n<4;n++){
      const int col = colBase + wc*64 + n*16 + (l&15);
      #pragma unroll
      for(int r=0;r<4;r++){
        const float v = acc[m][n][r];
        if(MODE==1){
          ((u16*)Cg)[z*sC + (long)(row0+r)*ldc + col] = f2bf(v);
        } else if(MODE==2){
          float o = disv[z*(long)sDis + row0 + r]*v + bias[col];
          o = o > 0.f ? o : 0.f;
          ((u16*)Cg)[z*sC + (long)(row0+r)*ldc + col] = f2bf(o);
        } else if(MODE==3){
          ((float*)Cg)[z*sC + (long)(row0+r)*ldc + col] = v + bias[col];
        } else if(MODE==4){
          const int row = row0 + r;
          if(row < BT_){
            const int bb = row/50, tt = row - bb*50;
            const int gate = col >> 9, ugg = col & 511;
            ((float*)Cg)[((((long)tt*8 + (bb>>3))*512 + ugg)*8 + (bb&7))*4 + gate] = v + bias[col];
          }
        } else if(MODE==5){
          const int row = row0 + r;
          const float o = (v + (row==col ? 1.f : 0.f)) * disv[z*(long)sDis + col];
          ((u16*)Cg)[z*sC + (long)row*ldc + col] = f2bf(o);
        }
      }
    }
  }
}

// ---------------- column-degree partial sums ----------------
__global__ void k_degpart(const u16* __restrict__ H, float* __restrict__ partial){
  const int c = blockIdx.z;
  const int col = blockIdx.x*256 + threadIdx.x;
  const int r0 = blockIdx.y*128;
  const u16* Hc = H + c*NN_;
  float s = 0.f;
  #pragma unroll 4
  for(int r=0;r<128;r++) s += bf2f(Hc[(long)(r0+r)*N_ + col]);
  partial[((long)c*16 + blockIdx.y)*N_ + col] = s;
}

// ---------------- dinv[c][m] = 1/(colsum - diag), guarded ----------------
__global__ void k_dinv(const u16* __restrict__ H, const float* __restrict__ partial,
                       float* __restrict__ dinvb){
  const int i = blockIdx.x*256 + threadIdx.x;
  const int c = i >> 11, m = i & (N_-1);
  float s = 0.f;
  #pragma unroll
  for(int p=0;p<16;p++) s += partial[((long)c*16 + p)*N_ + m];
  s -= bf2f(H[c*NN_ + (long)m*N_ + m]);
  dinvb[i] = s > 0.f ? 1.f/s : 0.f;
}

// ---------------- H[j][i] = (j==i) ? 0 : H*dinv[i] ----------------
__global__ void k_colscale(u16* __restrict__ H, const float* __restrict__ dinvb){
  const long i = (long)blockIdx.x*256 + threadIdx.x;
  const int c = blockIdx.y;
  const int j = (int)(i >> 11), ii = (int)(i & (N_-1));
  const long idx = c*NN_ + i;
  const float v = (j==ii) ? 0.f : bf2f(H[idx])*dinvb[c*N_ + ii];
  H[idx] = f2bf(v);
}

// ---------------- dis[c][j] = rsqrt(1 + sum_k HB2t[c][j][k]*mask[k]) ----------------
__global__ void k_dis(const u16* __restrict__ HB2t, const float* __restrict__ dinvb,
                      float* __restrict__ disv){
  const int c = blockIdx.y, j = blockIdx.x;
  const u16* r = HB2t + (c*(long)N_ + j)*N_;
  const float* dv = dinvb + c*N_;
  float s = 0.f;
  for(int i=threadIdx.x;i<N_;i+=256)
    if(dv[i] > 0.f) s += bf2f(r[i]);
  __shared__ float red[256];
  red[threadIdx.x] = s;
  __syncthreads();
  for(int st=128; st>0; st>>=1){
    if(threadIdx.x < st) red[threadIdx.x] += red[threadIdx.x+st];
    __syncthreads();
  }
  if(threadIdx.x==0){
    const float deg = red[0] + 1.f;
    disv[c*N_ + j] = deg > 0.f ? rsqrtf(deg) : 0.f;
  }
}

// ---------------- 3-in-1 transpose f32 -> bf16 ----------------
__global__ void k_transpose3(const float* __restrict__ gcnW, u16* __restrict__ Wt,
                             const float* __restrict__ lin1W, u16* __restrict__ l1Wt,
                             const float* __restrict__ scoreW, u16* __restrict__ sWt){
  const float* in; u16* out; int R, Cc;
  if(blockIdx.z==0){ in=gcnW;  out=Wt;   R=WIN_;     Cc=WOUT_; }
  else if(blockIdx.z==1){ in=lin1W; out=l1Wt; R=C_*WOUT_; Cc=WOUT_; }
  else { in=scoreW; out=sWt; R=N_; Cc=U_; }
  const int ti = blockIdx.x, tj = blockIdx.y;
  if(ti >= (Cc>>5) || tj >= (R>>5)) return;
  __shared__ float tt[32][33];
  const int x = threadIdx.x, y0 = threadIdx.y;
  #pragma unroll
  for(int i=0;i<4;i++){
    const int y = y0 + i*8;
    tt[y][x] = in[(long)(tj*32+y)*Cc + ti*32 + x];
  }
  __syncthreads();
  #pragma unroll
  for(int i=0;i<4;i++){
    const int y = y0 + i*8;
    out[(long)(ti*32+y)*R + tj*32 + x] = f2bf(tt[x][y]);
  }
}

// ---------------- dual cast f32 -> bf16 (X then Wih) ----------------
__global__ void k_cast2(const float* __restrict__ X, u16* __restrict__ Xbf,
                        const float* __restrict__ Wih, u16* __restrict__ Wihbf){
  const long i = (long)blockIdx.x*256 + threadIdx.x;
  if(i < (long)N_*WIN_) Xbf[i] = f2bf(X[i]);
  else { const long j = i - (long)N_*WIN_; Wihbf[j] = f2bf(Wih[j]); }
}

// ---------------- basket max-pool (grid 52x64; t>=50 writes pad zeros) ----------------
__global__ void k_pool(const float* __restrict__ seqs, const float* __restrict__ X_,
                       u16* __restrict__ bs){
  const int t = blockIdx.x, b = blockIdx.y;
  const int f = threadIdx.x;
  if(t >= T_){
    bs[(long)(BT_ + b*2 + (t-T_))*WOUT_ + f] = 0;
    return;
  }
  const float* mask = seqs + ((long)b*T_ + t)*N_;
  __shared__ int list[N_];
  __shared__ int cnt;
  if(f==0) cnt = 0;
  __syncthreads();
  for(int n0=f; n0<N_; n0+=256){
    if(mask[n0] > 0.f){
      int p = atomicAdd(&cnt, 1);
      list[p] = n0;
    }
  }
  __syncthreads();
  const int m = cnt;
  float mx = -3.4e38f;
  for(int i=0;i<m;i++)
    mx = fmaxf(mx, X_[(long)list[i]*WOUT_ + f]);
  bs[((long)b*T_ + t)*WOUT_ + f] = f2bf(m>0 ? mx : 0.f);
}

// ---------------- pack Whh: block (s) x wave (w) x lane (l), 2 row-frags x 16 k-frags ----------------
// A-frag row fr16=l&15 -> gate=fr16&3, u4=fr16>>2; grow = gate*512 + s*64 + w*8 + rf*4 + u4
__global__ void k_packWhh4(const float* __restrict__ Whh, u16* __restrict__ P){
  const long idx = (long)blockIdx.x*256 + threadIdx.x;  // 0..1048575
  const int e  = (int)(idx & 7);
  const int kk = (int)((idx >> 3) & 15);
  const int rf = (int)((idx >> 7) & 1);
  const int l  = (int)((idx >> 8) & 63);
  const int w  = (int)((idx >> 14) & 7);
  const int s  = (int)(idx >> 17);
  const int fr16 = l & 15;
  const int gate = fr16 & 3, u4 = fr16 >> 2;
  const int grow = gate*512 + s*64 + w*8 + rf*4 + u4;
  const int k = kk*32 + (l >> 4)*8 + e;
  P[idx] = f2bf(Whh[(long)grow*512 + k]);
}

// ---------------- Hg32 init: [8 grp][2 buf][8 bl][512 u]; buf0 = tag0|h0, buf1 = never ----------------
__global__ void k_hinit3(const float* __restrict__ h0, u32* __restrict__ Hg32){
  const int idx = blockIdx.x*256 + threadIdx.x;   // 0..65535
  if(idx < 32768){
    const int b = idx >> 9, u = idx & 511;
    Hg32[(b>>3)*8192 + (b&7)*512 + u] = (u32)f2bf(h0[idx]);
  } else {
    const int j = idx - 32768;
    const int b = j >> 9, u = j & 511;
    Hg32[(b>>3)*8192 + 4096 + (b&7)*512 + u] = 0xFFFF0000u;
  }
}

// ---------------- persistent LSTM v7: 8 single-XCD groups, tagged-data relaxed poll ----------------
// grp = blockIdx&7 (round-robin mod 8 -> one XCD per group); 8 blocks/group own 64 units each.
// Hg32 word = (tag<<16)|bf16(h). Happy path: relaxed agent load hits producer's store in the
// SAME XCD's L2 (coherent). Fallback: one acquire per failed sweep bounds staleness (r9 lesson).
__global__ __launch_bounds__(512) void k_lstm_all(
    const u16* __restrict__ WhhP, const float* __restrict__ Gq,
    const float* __restrict__ c0v, const int* __restrict__ seqlen,
    u32* __restrict__ Hg32, float* __restrict__ act)
{
  __shared__ u16 Hl[2*8*512];           // 16 KB, double-buffered
  const int tid = threadIdx.x;
  const int w = tid >> 6, l = tid & 63;
  const int grp = blockIdx.x & 7;
  const int s   = blockIdx.x >> 3;
  const int hi8 = (l >> 4) * 8;

  // Whh -> 32 bf16x8 (128 VGPR), held across all steps
  bf16x8 wreg[32];
  const u16* wp = WhhP + (((long)s*8 + w)*64 + l)*256;
  #pragma unroll
  for(int i=0;i<32;++i) wreg[i] = *(const bf16x8*)&wp[i*8];

  const int bl = l & 15;                // D col = batch (valid < 8; 8-15 duplicate)
  const bool valid = bl < 8;
  const int blr = bl & 7;
  const int bg = grp*8 + blr;
  const int ug0 = s*64 + w*8 + (l>>4);  // rf=0 unit; rf=1 adds +4
  float cst0 = 0.f, cst1 = 0.f;
  int sl = -2;
  if(valid){
    cst0 = c0v[bg*U_ + ug0];
    cst1 = c0v[bg*U_ + ug0 + 4];
    sl = seqlen[bg] - 1;
  }
  u32* Hgrp = Hg32 + grp*8192;          // [2][8][512]
  const int pb = tid >> 6, pu0 = (tid & 63) << 3;   // poll: batch pb, units pu0..pu0+7
  const int psw = pb << 3;
  const int rsw = blr << 3;
  const long gq0 = (((long)grp*512 + ug0)*8 + blr)*4;
  float4 gqn0 = *(const float4*)&Gq[gq0];
  float4 gqn1 = *(const float4*)&Gq[gq0 + 128];

  for(int t=0; t<T_; ++t){
    const float4 gqa = gqn0, gqb = gqn1;
    // ---- poll own 8 tagged words (tag==t) ----
    const u32* src = Hgrp + (t&1)*4096 + pb*512 + pu0;
    const u32 wt = (u32)t;
    u32 vals[8]; u32 need = 0xFFu;
    #pragma unroll
    for(int i=0;i<8;i++){
      u32 v = __hip_atomic_load(&src[i], __ATOMIC_RELAXED, __HIP_MEMORY_SCOPE_AGENT);
      if((v>>16)==wt){ vals[i]=v; need &= ~(1u<<i); }
    }
    while(need){
      const int fi = 31 - __builtin_clz(need);
      u32 v = __hip_atomic_load(&src[fi], __ATOMIC_ACQUIRE, __HIP_MEMORY_SCOPE_AGENT);
      if((v>>16)==wt){ vals[fi]=v; need &= ~(1u<<fi); }
      #pragma unroll
      for(int i=0;i<8;i++) if(need & (1u<<i)){
        u32 vv = __hip_atomic_load(&src[i], __ATOMIC_RELAXED, __HIP_MEMORY_SCOPE_AGENT);
        if((vv>>16)==wt){ vals[i]=vv; need &= ~(1u<<i); }
      }
    }
    // prefetch next-step Gq (in flight across repack+barrier+MFMA)
    if(t+1 < T_){
      gqn0 = *(const float4*)&Gq[(long)(t+1)*131072 + gq0];
      gqn1 = *(const float4*)&Gq[(long)(t+1)*131072 + gq0 + 128];
    }
    // ---- repack into Hl[t&1] (one 16B write/thread) ----
    uint4 q;
    q.x=(vals[0]&0xffffu)|(vals[1]<<16);  q.y=(vals[2]&0xffffu)|(vals[3]<<16);
    q.z=(vals[4]&0xffffu)|(vals[5]<<16);  q.w=(vals[6]&0xffffu)|(vals[7]<<16);
    *(uint4*)&Hl[(t&1)*4096 + (pb<<9) + (pu0 ^ psw)] = q;
    __syncthreads();                      // one barrier per step

    // ---- gates: 32 MFMA/wave, W in regs, B shared across both row-frags ----
    const u16* Hb_ = &Hl[(t&1)*4096 + (blr<<9)];
    f32x4 acc0 = f32x4{0.f,0.f,0.f,0.f};
    f32x4 acc1 = f32x4{0.f,0.f,0.f,0.f};
    #pragma unroll
    for(int kk=0; kk<16; ++kk){
      const int ke = kk*32 + hi8;
      bf16x8 bb = *(const bf16x8*)&Hb_[ke ^ rsw];
      acc0 = __builtin_amdgcn_mfma_f32_16x16x32_bf16(wreg[kk],    bb, acc0, 0, 0, 0);
      acc1 = __builtin_amdgcn_mfma_f32_16x16x32_bf16(wreg[16+kk], bb, acc1, 0, 0, 0);
    }

    if(valid){
      {
        const float a0=acc0[0]+gqa.x, a1=acc0[1]+gqa.y, a2=acc0[2]+gqa.z, a3=acc0[3]+gqa.w;
        const float ig=1.f/(1.f+expf(-a0)), fg=1.f/(1.f+expf(-a1));
        const float gg=tanhf(a2), og=1.f/(1.f+expf(-a3));
        cst0 = fg*cst0 + ig*gg;
        const float h = og*tanhf(cst0);
        if(t+1 < T_)
          __hip_atomic_store(&Hgrp[((t+1)&1)*4096 + blr*512 + ug0],
                             (u32)f2bf(h) | ((u32)(t+1)<<16),
                             __ATOMIC_RELAXED, __HIP_MEMORY_SCOPE_AGENT);
        if(sl==t) act[bg*U_ + ug0] = h;
      }
      {
        const float a0=acc1[0]+gqb.x, a1=acc1[1]+gqb.y, a2=acc1[2]+gqb.z, a3=acc1[3]+gqb.w;
        const float ig=1.f/(1.f+expf(-a0)), fg=1.f/(1.f+expf(-a1));
        const float gg=tanhf(a2), og=1.f/(1.f+expf(-a3));
        cst1 = fg*cst1 + ig*gg;
        const float h = og*tanhf(cst1);
        if(t+1 < T_)
          __hip_atomic_store(&Hgrp[((t+1)&1)*4096 + blr*512 + ug0 + 4],
                             (u32)f2bf(h) | ((u32)(t+1)<<16),
                             __ATOMIC_RELAXED, __HIP_MEMORY_SCOPE_AGENT);
        if(sl==t) act[bg*U_ + ug0 + 4] = h;
      }
    }
  }
}

// ---------------- out[b][n] = sigmoid(actual[b] . sWt[:,n])  (f32 out) ----------------
__global__ void k_score(const float* __restrict__ actual, const u16* __restrict__ sWt,
                        float* __restrict__ out){
  const int n = blockIdx.x*256 + threadIdx.x;
  const int b = blockIdx.y;
  const float* ab = actual + (long)b*U_;
  float s = 0.f;
  for(int uu=0; uu<U_; uu++) s += ab[uu]*bf2f(sWt[(long)uu*N_ + n]);
  out[(long)b*N_ + n] = 1.f/(1.f + expf(-s));
}

extern "C" void kernel_launch(void* const* d_in, const int* in_sizes, int n_in,
                              void* d_out, int out_size, void* d_ws, size_t ws_size,
                              hipStream_t stream){
  (void)in_sizes; (void)n_in; (void)out_size; (void)ws_size;
  const float* A      = (const float*)d_in[0];
  const float* X      = (const float*)d_in[1];
  const float* seqs   = (const float*)d_in[2];
  const int*   seqlen = (const int*)d_in[3];
  const float* h0     = (const float*)d_in[4];
  const float* c0     = (const float*)d_in[5];
  const float* gtw1   = (const float*)d_in[6];
  const float* gtw2   = (const float*)d_in[7];
  const float* gtw3   = (const float*)d_in[8];
  const float* gcnW   = (const float*)d_in[9];
  const float* gcnB   = (const float*)d_in[10];
  const float* lin1W  = (const float*)d_in[11];
  const float* lin1B  = (const float*)d_in[12];
  const float* Wih    = (const float*)d_in[13];
  const float* Whh    = (const float*)d_in[14];
  const float* bihp   = (const float*)d_in[15];
  const float* bhhp   = (const float*)d_in[16];
  const float* scoreW = (const float*)d_in[17];

  char* ws = (char*)d_ws;
  u16* buf0 = (u16*)(ws + 0);
  u16* buf1 = (u16*)(ws + 16777216);
  u16* buf2 = (u16*)(ws + 33554432);
  char* S0  = ws + 50331648;
  float* filt  = (float*)(S0 + 0);
  float* disv  = (float*)(S0 + 1024);
  u16*  Wt     = (u16*) (S0 + 17408);
  u16*  XWt    = (u16*) (S0 + 148480);
  u16*  catb   = (u16*) (S0 + 1197056);
  u16*  l1Wt   = (u16*) (S0 + 3294208);
  float* Xo    = (float*)(S0 + 3556352);
  u16*  bs     = (u16*) (S0 + 5653504);
  float* act   = (float*)(S0 + 7357440);
  u16*  sWt    = (u16*) (S0 + 7488512);
  u16*  WhhB   = (u16*) (S0 + 9585664);
  u16*  Xbf    = (u16*) (S0 + 11682816);
  u16*  Wihbf  = (u16*) (S0 + 12731392);
  float* bsum  = (float*)(S0 + 13779968);
  float* degp  = (float*)(S0 + 14050304);
  float* dinvb = (float*)(S0 + 14312448);
  u32*  Hg32   = (u32*) (S0 + 14328832);   // 256 KB: 8 grp x 2 buf x 8 bl x 512 u
  u16* HA   = buf0;
  u16* HBt  = buf1;
  u16* Hb   = buf2;
  u16* HB2t = buf0;
  u16* Pd   = buf1;
  float* Gq = (float*)ws;   // 26.2 MiB over buf0+buf1 (dead by then)

  k_prep0<<<dim3(8), 256, 0, stream>>>(gtw1, gtw2, gtw3, filt, bihp, bhhp, bsum);
  k_combineAll<<<dim3(N_/32, N_/32), dim3(32,8), 0, stream>>>(A, filt, HA, HBt);
  k_transpose3<<<dim3(16, 64, 3), dim3(32,8), 0, stream>>>(gcnW, Wt, lin1W, l1Wt, scoreW, sWt);
  k_cast2<<<dim3(4096), 256, 0, stream>>>(X, Xbf, Wih, Wihbf);
  gemm_bt<1><<<dim3(16,16,C_), 256, 0, stream>>>(HA, HBt, Hb, N_, N_, NN_, NN_, NN_, nullptr, 0, nullptr);
  k_degpart<<<dim3(8, 16, C_), 256, 0, stream>>>(Hb, degp);
  k_dinv<<<dim3(16), 256, 0, stream>>>(Hb, degp, dinvb);
  k_colscale<<<dim3(NN_/256, C_), 256, 0, stream>>>(Hb, dinvb);
  k_combineT2<<<dim3(N_/32, N_/32), dim3(32,8), 0, stream>>>(A, filt + 2*C_*E_, HB2t);
  k_dis<<<dim3(N_, C_), 256, 0, stream>>>(HB2t, dinvb, disv);
  gemm_bt<5><<<dim3(16,16,C_), 256, 0, stream>>>(HB2t, Hb, Pd, N_, N_, NN_, NN_, NN_, disv, N_, nullptr);
  gemm_bt<1><<<dim3(N_/128, WOUT_/128, 1), 256, 0, stream>>>(Wt, Xbf, XWt, WIN_, N_, 0, 0, 0, nullptr, 0, nullptr);
  gemm_bt<2><<<dim3(WOUT_/128, N_/128, C_), 256, 0, stream>>>(Pd, XWt, catb, N_, C_*WOUT_, NN_, 0, WOUT_, disv, N_, gcnB);
  gemm_bt<3><<<dim3(WOUT_/128, N_/128, 1), 256, 0, stream>>>(catb, l1Wt, Xo, C_*WOUT_, WOUT_, 0, 0, 0, nullptr, 0, lin1B);
  k_pool<<<dim3(52, B_), 256, 0, stream>>>(seqs, Xo, bs);
  gemm_bt<4><<<dim3((4*U_)/128, BTP_/128, 1), 256, 0, stream>>>(bs, Wihbf, Gq, WOUT_, 0, 0, 0, 0, nullptr, 0, bsum);
  k_packWhh4<<<dim3(4096), 256, 0, stream>>>(Whh, WhhB);
  k_hinit3<<<dim3(256), 256, 0, stream>>>(h0, Hg32);
  k_lstm_all<<<dim3(64), 512, 0, stream>>>(WhhB, Gq, c0, seqlen, Hg32, act);
  k_score<<<dim3(N_/256, B_), 256, 0, stream>>>(act, sWt, (float*)d_out);
}

// Round 12
// 561.964 us; speedup vs baseline: 5.9410x; 1.2287x over previous
//
#include <hip/hip_runtime.h>
#include <stdint.h>

#define E_ 3
#define C_ 2
#define N_ 2048
#define B_ 64
#define T_ 50
#define WIN_ 256
#define WOUT_ 256
#define U_ 512
#define BT_ (B_*T_)
#define BTP_ 3328

typedef unsigned short u16;
typedef unsigned int u32;
typedef __bf16 bf16x8 __attribute__((ext_vector_type(8)));
typedef float f32x4 __attribute__((ext_vector_type(4)));

#define NN_ (2048LL*2048LL)

__device__ __forceinline__ float bf2f(u16 u){
  u32 x = ((u32)u) << 16; return __builtin_bit_cast(float, x);
}
__device__ __forceinline__ u16 f2bf(float f){
  u32 x = __builtin_bit_cast(u32, f);
  u32 r = (x + 0x7fffu + ((x >> 16) & 1u)) >> 16;
  return (u16)r;
}

__device__ __forceinline__ void gload16(const u16* g, u16* l){
  __builtin_amdgcn_global_load_lds((const __attribute__((address_space(1))) u32*)g,
                                   (__attribute__((address_space(3))) u32*)l, 16, 0, 0);
}

// ---------------- prep0: softmax filters + bsum + flag zero ----------------
__global__ void k_prep0(const float* __restrict__ w1, const float* __restrict__ w2,
                        const float* __restrict__ w3, float* __restrict__ filt,
                        const float* __restrict__ bih, const float* __restrict__ bhh,
                        float* __restrict__ bsum, u32* __restrict__ flagv){
  const int i = blockIdx.x*256 + threadIdx.x;
  bsum[i] = bih[i] + bhh[i];
  flagv[i] = 0;
  if(blockIdx.x==0 && threadIdx.x < 3*C_){
    const int t = threadIdx.x;
    const int fi = t / C_, c = t % C_;
    const float* w = (fi==0) ? w1 : ((fi==1) ? w2 : w3);
    float v[E_]; float mx = -3.4e38f;
    for(int e=0;e<E_;e++){ v[e] = w[c*E_+e]; mx = fmaxf(mx, v[e]); }
    float s = 0.f;
    for(int e=0;e<E_;e++){ v[e] = expf(v[e]-mx); s += v[e]; }
    for(int e=0;e<E_;e++) filt[(fi*C_+c)*E_ + e] = v[e]/s;
  }
}

// ---------------- fused combine: HA (direct) + HBt (transposed), A read ONCE ----------------
__global__ void k_combineAll(const float* __restrict__ A, const float* __restrict__ filt,
                             u16* __restrict__ HA, u16* __restrict__ HBt){
  __shared__ float te[3][32][33];
  const int ti = blockIdx.x, tj = blockIdx.y;
  const int x = threadIdx.x, y0 = threadIdx.y;
  #pragma unroll
  for(int i=0;i<4;i++){
    const int y = y0 + i*8;
    const long base = (long)(tj*32+y)*N_ + ti*32 + x;
    const float a0 = A[0*NN_+base], a1 = A[1*NN_+base], a2 = A[2*NN_+base];
    te[0][y][x]=a0; te[1][y][x]=a1; te[2][y][x]=a2;
    #pragma unroll
    for(int c=0;c<C_;c++)
      HA[c*NN_ + base] = f2bf(filt[c*E_]*a0 + filt[c*E_+1]*a1 + filt[c*E_+2]*a2);
  }
  __syncthreads();
  #pragma unroll
  for(int i=0;i<4;i++){
    const int y = y0 + i*8;
    const long ob = (long)(ti*32+y)*N_ + tj*32 + x;
    const float a0=te[0][x][y], a1=te[1][x][y], a2=te[2][x][y];
    #pragma unroll
    for(int c=0;c<C_;c++)
      HBt[c*NN_+ob] = f2bf(filt[(C_+c)*E_]*a0 + filt[(C_+c)*E_+1]*a1 + filt[(C_+c)*E_+2]*a2);
  }
}

// ---------------- HB2t both channels, one pass over A ----------------
__global__ void k_combineT2(const float* __restrict__ A, const float* __restrict__ f,
                            u16* __restrict__ outp){
  __shared__ float te[3][32][33];
  const int ti = blockIdx.x, tj = blockIdx.y;
  const int x = threadIdx.x, y0 = threadIdx.y;
  #pragma unroll
  for(int i=0;i<4;i++){
    const int y = y0 + i*8;
    const long base = (long)(tj*32+y)*N_ + ti*32 + x;
    te[0][y][x]=A[0*NN_+base]; te[1][y][x]=A[1*NN_+base]; te[2][y][x]=A[2*NN_+base];
  }
  __syncthreads();
  #pragma unroll
  for(int i=0;i<4;i++){
    const int y = y0 + i*8;
    const long ob = (long)(ti*32+y)*N_ + tj*32 + x;
    const float a0=te[0][x][y], a1=te[1][x][y], a2=te[2][x][y];
    #pragma unroll
    for(int c=0;c<C_;c++)
      outp[c*NN_+ob] = f2bf(f[c*E_]*a0 + f[c*E_+1]*a1 + f[c*E_+2]*a2);
  }
}

// ---------------- MFMA GEMM: OUT[i][j] = sum_k A[i][k]*B[j][k] ----------------
// MODE 1: bf16 raw; 2: bf16 relu(dis[row]*acc+bias[col]); 3: f32 acc+bias[col];
// MODE 4: Gq scatter (16-batch groups); MODE 5: bf16 (acc+(row==col))*disv[col];
// MODE 6: f32 sigmoid(acc), rows < B_ only (score head)
template<int MODE>
__global__ __launch_bounds__(256) void gemm_bt(
    const u16* __restrict__ Ag, const u16* __restrict__ Bg, void* __restrict__ Cg,
    int K, int ldc, long sA, long sB, long sC,
    const float* __restrict__ disv, int sDis, const float* __restrict__ bias)
{
  __shared__ u16 At[128*32];
  __shared__ u16 Bt[128*32];
  const int tid = threadIdx.x;
  const int w = tid >> 6, l = tid & 63;
  const int z = blockIdx.z;
  const u16* Ab = Ag + (long)z*sA;
  const u16* Bb = Bg + (long)z*sB;
  const int rowBase = blockIdx.y*128;
  const int colBase = blockIdx.x*128;

  f32x4 acc[4][4];
  #pragma unroll
  for(int i=0;i<4;i++)
    #pragma unroll
    for(int j=0;j<4;j++)
      acc[i][j] = f32x4{0.f,0.f,0.f,0.f};

  const int wr = w >> 1, wc = w & 1;
  const int arow0 = (w*2+0)*16 + (l>>2);
  const int arow1 = (w*2+1)*16 + (l>>2);
  const int kc = (((l&3) ^ ((l>>2)&3)))*8;
  const int frow = l & 15;
  const int fkc = l >> 4;

  const int nk = K >> 5;
  for(int kt=0; kt<nk; ++kt){
    const int k0 = kt << 5;
    gload16(Ab + (long)(rowBase+arow0)*K + k0 + kc, &At[(w*2+0)*512]);
    gload16(Ab + (long)(rowBase+arow1)*K + k0 + kc, &At[(w*2+1)*512]);
    gload16(Bb + (long)(colBase+arow0)*K + k0 + kc, &Bt[(w*2+0)*512]);
    gload16(Bb + (long)(colBase+arow1)*K + k0 + kc, &Bt[(w*2+1)*512]);
    __syncthreads();
    bf16x8 af[4], bfv[4];
    #pragma unroll
    for(int m=0;m<4;m++){
      const int rr = wr*64 + m*16 + frow;
      af[m] = *(const bf16x8*)&At[rr*32 + ((fkc ^ (rr&3))<<3)];
    }
    #pragma unroll
    for(int n=0;n<4;n++){
      const int rr = wc*64 + n*16 + frow;
      bfv[n] = *(const bf16x8*)&Bt[rr*32 + ((fkc ^ (rr&3))<<3)];
    }
    #pragma unroll
    for(int m=0;m<4;m++)
      #pragma unroll
      for(int n=0;n<4;n++)
        acc[m][n] = __builtin_amdgcn_mfma_f32_16x16x32_bf16(af[m], bfv[n], acc[m][n], 0, 0, 0);
    __syncthreads();
  }

  #pragma unroll
  for(int m=0;m<4;m++){
    const int row0 = rowBase + wr*64 + m*16 + (l>>4)*4;
    #pragma unroll
    for(int n=0;n<4;n++){
      const int col = colBase + wc*64 + n*16 + (l&15);
      #pragma unroll
      for(int r=0;r<4;r++){
        const float v = acc[m][n][r];
        if(MODE==1){
          ((u16*)Cg)[z*sC + (long)(row0+r)*ldc + col] = f2bf(v);
        } else if(MODE==2){
          float o = disv[z*(long)sDis + row0 + r]*v + bias[col];
          o = o > 0.f ? o : 0.f;
          ((u16*)Cg)[z*sC + (long)(row0+r)*ldc + col] = f2bf(o);
        } else if(MODE==3){
          ((float*)Cg)[z*sC + (long)(row0+r)*ldc + col] = v + bias[col];
        } else if(MODE==4){
          const int row = row0 + r;
          if(row < BT_){
            const int bb = row/50, tt = row - bb*50;
            const int gate = col >> 9, ugg = col & 511;
            ((float*)Cg)[((((long)tt*4 + (bb>>4))*512 + ugg)*16 + (bb&15))*4 + gate] = v + bias[col];
          }
        } else if(MODE==5){
          const int row = row0 + r;
          const float o = (v + (row==col ? 1.f : 0.f)) * disv[z*(long)sDis + col];
          ((u16*)Cg)[z*sC + (long)row*ldc + col] = f2bf(o);
        } else if(MODE==6){
          const int row = row0 + r;
          if(row < B_)
            ((float*)Cg)[(long)row*ldc + col] = 1.f/(1.f + expf(-v));
        }
      }
    }
  }
}

// ---------------- column-degree partial sums ----------------
__global__ void k_degpart(const u16* __restrict__ H, float* __restrict__ partial){
  const int c = blockIdx.z;
  const int col = blockIdx.x*256 + threadIdx.x;
  const int r0 = blockIdx.y*128;
  const u16* Hc = H + c*NN_;
  float s = 0.f;
  #pragma unroll 4
  for(int r=0;r<128;r++) s += bf2f(Hc[(long)(r0+r)*N_ + col]);
  partial[((long)c*16 + blockIdx.y)*N_ + col] = s;
}

// ---------------- dinv[c][m] = 1/(colsum - diag), guarded ----------------
__global__ void k_dinv(const u16* __restrict__ H, const float* __restrict__ partial,
                       float* __restrict__ dinvb){
  const int i = blockIdx.x*256 + threadIdx.x;
  const int c = i >> 11, m = i & (N_-1);
  float s = 0.f;
  #pragma unroll
  for(int p=0;p<16;p++) s += partial[((long)c*16 + p)*N_ + m];
  s -= bf2f(H[c*NN_ + (long)m*N_ + m]);
  dinvb[i] = s > 0.f ? 1.f/s : 0.f;
}

// ---------------- H[j][i] = (j==i) ? 0 : H*dinv[i] ----------------
__global__ void k_colscale(u16* __restrict__ H, const float* __restrict__ dinvb){
  const long i = (long)blockIdx.x*256 + threadIdx.x;
  const int c = blockIdx.y;
  const int j = (int)(i >> 11), ii = (int)(i & (N_-1));
  const long idx = c*NN_ + i;
  const float v = (j==ii) ? 0.f : bf2f(H[idx])*dinvb[c*N_ + ii];
  H[idx] = f2bf(v);
}

// ---------------- dis[c][j] = rsqrt(1 + sum_k HB2t[c][j][k]*mask[k]) ----------------
__global__ void k_dis(const u16* __restrict__ HB2t, const float* __restrict__ dinvb,
                      float* __restrict__ disv){
  const int c = blockIdx.y, j = blockIdx.x;
  const u16* r = HB2t + (c*(long)N_ + j)*N_;
  const float* dv = dinvb + c*N_;
  float s = 0.f;
  for(int i=threadIdx.x;i<N_;i+=256)
    if(dv[i] > 0.f) s += bf2f(r[i]);
  __shared__ float red[256];
  red[threadIdx.x] = s;
  __syncthreads();
  for(int st=128; st>0; st>>=1){
    if(threadIdx.x < st) red[threadIdx.x] += red[threadIdx.x+st];
    __syncthreads();
  }
  if(threadIdx.x==0){
    const float deg = red[0] + 1.f;
    disv[c*N_ + j] = deg > 0.f ? rsqrtf(deg) : 0.f;
  }
}

// ---------------- 2-in-1 transpose f32 -> bf16 ----------------
__global__ void k_transpose3(const float* __restrict__ gcnW, u16* __restrict__ Wt,
                             const float* __restrict__ lin1W, u16* __restrict__ l1Wt){
  const float* in; u16* out; int R, Cc;
  if(blockIdx.z==0){ in=gcnW;  out=Wt;   R=WIN_;     Cc=WOUT_; }
  else { in=lin1W; out=l1Wt; R=C_*WOUT_; Cc=WOUT_; }
  const int ti = blockIdx.x, tj = blockIdx.y;
  if(ti >= (Cc>>5) || tj >= (R>>5)) return;
  __shared__ float tt[32][33];
  const int x = threadIdx.x, y0 = threadIdx.y;
  #pragma unroll
  for(int i=0;i<4;i++){
    const int y = y0 + i*8;
    tt[y][x] = in[(long)(tj*32+y)*Cc + ti*32 + x];
  }
  __syncthreads();
  #pragma unroll
  for(int i=0;i<4;i++){
    const int y = y0 + i*8;
    out[(long)(ti*32+y)*R + tj*32 + x] = f2bf(tt[x][y]);
  }
}

// ---------------- triple cast f32 -> bf16 (X, Wih, scoreW) ----------------
__global__ void k_cast3(const float* __restrict__ X, u16* __restrict__ Xbf,
                        const float* __restrict__ Wih, u16* __restrict__ Wihbf,
                        const float* __restrict__ scoreW, u16* __restrict__ sWbf){
  const long i = (long)blockIdx.x*256 + threadIdx.x;
  if(i < (long)N_*WIN_) Xbf[i] = f2bf(X[i]);
  else if(i < (long)N_*WIN_ + 4*U_*WOUT_){
    const long j = i - (long)N_*WIN_; Wihbf[j] = f2bf(Wih[j]);
  } else {
    const long j = i - (long)N_*WIN_ - 4*U_*WOUT_; sWbf[j] = f2bf(scoreW[j]);
  }
}

// ---------------- basket max-pool (grid 52x64; t>=50 writes pad zeros) ----------------
__global__ void k_pool(const float* __restrict__ seqs, const float* __restrict__ X_,
                       u16* __restrict__ bs){
  const int t = blockIdx.x, b = blockIdx.y;
  const int f = threadIdx.x;
  if(t >= T_){
    bs[(long)(BT_ + b*2 + (t-T_))*WOUT_ + f] = 0;
    return;
  }
  const float* mask = seqs + ((long)b*T_ + t)*N_;
  __shared__ int list[N_];
  __shared__ int cnt;
  if(f==0) cnt = 0;
  __syncthreads();
  for(int n0=f; n0<N_; n0+=256){
    if(mask[n0] > 0.f){
      int p = atomicAdd(&cnt, 1);
      list[p] = n0;
    }
  }
  __syncthreads();
  const int m = cnt;
  float mx = -3.4e38f;
  for(int i=0;i<m;i++)
    mx = fmaxf(mx, X_[(long)list[i]*WOUT_ + f]);
  bs[((long)b*T_ + t)*WOUT_ + f] = f2bf(m>0 ? mx : 0.f);
}

// ---------------- pack Whh for register-resident A-frags (r8 layout) ----------------
__global__ void k_packWhh3(const float* __restrict__ Whh, u16* __restrict__ P){
  const long idx = (long)blockIdx.x*256 + threadIdx.x;
  const int e  = (int)(idx & 7);
  const int kk = (int)((idx >> 3) & 15);
  const int l  = (int)((idx >> 7) & 63);
  const int w  = (int)((idx >> 13) & 7);
  const int s  = (int)(idx >> 16);
  const int lr = w*16 + (l & 15);
  const int gam = lr & 3, ui = lr >> 2;
  const int grow = gam*512 + s*32 + ui;
  const int k = kk*32 + (l >> 4)*8 + e;
  P[idx] = f2bf(Whh[(long)grow*512 + k]);
}

// ---------------- Hglob init: per-group [16 b][512 u] pre-swizzled ----------------
__global__ void k_hinit(const float* __restrict__ h0, u16* __restrict__ Hglob){
  const int idx = blockIdx.x*256 + threadIdx.x;
  const int b = idx >> 9, u = idx & 511;
  const int grp = b >> 4, bl = b & 15;
  Hglob[grp*16384 + (bl << 9) + (u ^ ((bl & 7) << 3))] = f2bf(h0[idx]);
}

// ---------------- persistent LSTM (r8-proven): 4 XCD-affine groups x 16 blocks ----------------
__global__ __launch_bounds__(512) void k_lstm_all(
    const u16* __restrict__ WhhP, const float* __restrict__ Gq,
    const float* __restrict__ c0v, const int* __restrict__ seqlen,
    u16* __restrict__ Hglob, u32* __restrict__ flagv, u16* __restrict__ act)
{
  __shared__ u16 Hl[16*512];
  const int tid = threadIdx.x;
  const int w = tid >> 6, l = tid & 63;
  const int grp = blockIdx.x & 3, s = blockIdx.x >> 2;
  const int fr = l & 15, hi = l >> 4;

  bf16x8 wreg[16];
  const u16* wp = WhhP + (((long)s*8 + w)*64 + l)*128;
  #pragma unroll
  for(int kk=0; kk<16; ++kk)
    wreg[kk] = *(const bf16x8*)&wp[kk*8];

  const int ug = s*32 + w*4 + hi;
  const int bl = fr;
  const int bg = grp*16 + bl;
  float cst = c0v[bg*U_ + ug];
  const int sl = seqlen[bg] - 1;
  u16* Hbase = Hglob + grp*16384;
  const int hswz = (bl & 7) << 3;
  const int fi = (grp*16 + fr)*32;
  const long gqbase = (((long)grp*512 + ug)*16 + bl)*4;
  float4 gq_nxt = *(const float4*)&Gq[gqbase];

  for(int t=0; t<T_; ++t){
    const float4 gq = gq_nxt;
    const u16* Hin = Hbase + (t & 1)*8192;
    #pragma unroll
    for(int r=0; r<2; ++r)
      gload16(Hin + (r*8 + w)*512 + l*8, &Hl[(r*8 + w)*512]);
    __syncthreads();

    f32x4 acc = f32x4{0.f,0.f,0.f,0.f};
    #pragma unroll
    for(int kk=0; kk<16; ++kk){
      const int ke = kk*32 + hi*8;
      bf16x8 bb = *(const bf16x8*)&Hl[(bl << 9) + (ke ^ hswz)];
      acc = __builtin_amdgcn_mfma_f32_16x16x32_bf16(wreg[kk], bb, acc, 0, 0, 0);
    }

    if(t+1 < T_)
      gq_nxt = *(const float4*)&Gq[(long)(t+1)*(4*2048*16) + gqbase];

    const float a0 = acc[0] + gq.x;
    const float a1 = acc[1] + gq.y;
    const float a2 = acc[2] + gq.z;
    const float a3 = acc[3] + gq.w;
    const float ig = 1.f/(1.f + expf(-a0));
    const float fg = 1.f/(1.f + expf(-a1));
    const float gg = tanhf(a2);
    const float og = 1.f/(1.f + expf(-a3));
    cst = fg*cst + ig*gg;
    const float h = og*tanhf(cst);
    u16* Hout = Hbase + ((t+1) & 1)*8192;
    Hout[(bl << 9) + (ug ^ hswz)] = f2bf(h);
    if(sl == t) act[bg*U_ + ug] = f2bf(h);

    if(t == T_-1) break;
    __syncthreads();
    if(tid == 0)
      __hip_atomic_store(&flagv[(grp*16 + s)*32], (u32)(t+1),
                         __ATOMIC_RELEASE, __HIP_MEMORY_SCOPE_AGENT);
    if(w == 0){
      while(__hip_atomic_load(&flagv[fi], __ATOMIC_ACQUIRE,
                              __HIP_MEMORY_SCOPE_AGENT) <= (u32)t){
        __builtin_amdgcn_s_sleep(1);
      }
    }
    __syncthreads();
  }
}

extern "C" void kernel_launch(void* const* d_in, const int* in_sizes, int n_in,
                              void* d_out, int out_size, void* d_ws, size_t ws_size,
                              hipStream_t stream){
  (void)in_sizes; (void)n_in; (void)out_size; (void)ws_size;
  const float* A      = (const float*)d_in[0];
  const float* X      = (const float*)d_in[1];
  const float* seqs   = (const float*)d_in[2];
  const int*   seqlen = (const int*)d_in[3];
  const float* h0     = (const float*)d_in[4];
  const float* c0     = (const float*)d_in[5];
  const float* gtw1   = (const float*)d_in[6];
  const float* gtw2   = (const float*)d_in[7];
  const float* gtw3   = (const float*)d_in[8];
  const float* gcnW   = (const float*)d_in[9];
  const float* gcnB   = (const float*)d_in[10];
  const float* lin1W  = (const float*)d_in[11];
  const float* lin1B  = (const float*)d_in[12];
  const float* Wih    = (const float*)d_in[13];
  const float* Whh    = (const float*)d_in[14];
  const float* bihp   = (const float*)d_in[15];
  const float* bhhp   = (const float*)d_in[16];
  const float* scoreW = (const float*)d_in[17];

  char* ws = (char*)d_ws;
  u16* buf0 = (u16*)(ws + 0);
  u16* buf1 = (u16*)(ws + 16777216);
  u16* buf2 = (u16*)(ws + 33554432);
  char* S0  = ws + 50331648;
  float* filt  = (float*)(S0 + 0);
  float* disv  = (float*)(S0 + 1024);
  u16*  Wt     = (u16*) (S0 + 17408);
  u16*  XWt    = (u16*) (S0 + 148480);
  u16*  catb   = (u16*) (S0 + 1197056);
  u16*  l1Wt   = (u16*) (S0 + 3294208);
  float* Xo    = (float*)(S0 + 3556352);
  u16*  bs     = (u16*) (S0 + 5653504);
  u16*  act    = (u16*) (S0 + 7357440);    // 128x512 bf16 (rows 64..127 = pad)
  u16*  sWbf   = (u16*) (S0 + 7488512);    // scoreW bf16, 2048x512
  u16*  WhhB   = (u16*) (S0 + 9585664);
  u16*  Xbf    = (u16*) (S0 + 11682816);
  u16*  Wihbf  = (u16*) (S0 + 12731392);
  float* bsum  = (float*)(S0 + 13779968);
  u16*  Hglob  = (u16*) (S0 + 13788160);   // 4 grp x 16384 u16 = 128 KB
  u32*  flagv  = (u32*) (S0 + 13919232);   // 2048 u32
  float* degp  = (float*)(S0 + 14050304);
  float* dinvb = (float*)(S0 + 14312448);
  u16* HA   = buf0;
  u16* HBt  = buf1;
  u16* Hb   = buf2;
  u16* HB2t = buf0;
  u16* Pd   = buf1;
  float* Gq = (float*)ws;   // 26.2 MiB over buf0+buf1 (dead by then)

  k_prep0<<<dim3(8), 256, 0, stream>>>(gtw1, gtw2, gtw3, filt, bihp, bhhp, bsum, flagv);
  k_combineAll<<<dim3(N_/32, N_/32), dim3(32,8), 0, stream>>>(A, filt, HA, HBt);
  k_transpose3<<<dim3(16, 64, 2), dim3(32,8), 0, stream>>>(gcnW, Wt, lin1W, l1Wt);
  k_cast3<<<dim3(8192), 256, 0, stream>>>(X, Xbf, Wih, Wihbf, scoreW, sWbf);
  gemm_bt<1><<<dim3(16,16,C_), 256, 0, stream>>>(HA, HBt, Hb, N_, N_, NN_, NN_, NN_, nullptr, 0, nullptr);
  k_degpart<<<dim3(8, 16, C_), 256, 0, stream>>>(Hb, degp);
  k_dinv<<<dim3(16), 256, 0, stream>>>(Hb, degp, dinvb);
  k_colscale<<<dim3(NN_/256, C_), 256, 0, stream>>>(Hb, dinvb);
  k_combineT2<<<dim3(N_/32, N_/32), dim3(32,8), 0, stream>>>(A, filt + 2*C_*E_, HB2t);
  k_dis<<<dim3(N_, C_), 256, 0, stream>>>(HB2t, dinvb, disv);
  gemm_bt<5><<<dim3(16,16,C_), 256, 0, stream>>>(HB2t, Hb, Pd, N_, N_, NN_, NN_, NN_, disv, N_, nullptr);
  gemm_bt<1><<<dim3(N_/128, WOUT_/128, 1), 256, 0, stream>>>(Wt, Xbf, XWt, WIN_, N_, 0, 0, 0, nullptr, 0, nullptr);
  gemm_bt<2><<<dim3(WOUT_/128, N_/128, C_), 256, 0, stream>>>(Pd, XWt, catb, N_, C_*WOUT_, NN_, 0, WOUT_, disv, N_, gcnB);
  gemm_bt<3><<<dim3(WOUT_/128, N_/128, 1), 256, 0, stream>>>(catb, l1Wt, Xo, C_*WOUT_, WOUT_, 0, 0, 0, nullptr, 0, lin1B);
  k_pool<<<dim3(52, B_), 256, 0, stream>>>(seqs, Xo, bs);
  gemm_bt<4><<<dim3((4*U_)/128, BTP_/128, 1), 256, 0, stream>>>(bs, Wihbf, Gq, WOUT_, 0, 0, 0, 0, nullptr, 0, bsum);
  k_packWhh3<<<dim3(4096), 256, 0, stream>>>(Whh, WhhB);
  k_hinit<<<dim3(128), 256, 0, stream>>>(h0, Hglob);
  k_lstm_all<<<dim3(64), 512, 0, stream>>>(WhhB, Gq, c0, seqlen, Hglob, flagv, act);
  // out = sigmoid(act @ scoreW^T) via MFMA (rows >= 64 discarded)
  gemm_bt<6><<<dim3(N_/128, 1, 1), 256, 0, stream>>>(act, sWbf, (float*)d_out, U_, N_, 0, 0, 0, nullptr, 0, nullptr);
}

// Round 13
// 521.339 us; speedup vs baseline: 6.4039x; 1.0779x over previous
//
#include <hip/hip_runtime.h>
#include <stdint.h>

#define E_ 3
#define C_ 2
#define N_ 2048
#define B_ 64
#define T_ 50
#define WIN_ 256
#define WOUT_ 256
#define U_ 512
#define BT_ (B_*T_)
#define BTP_ 3328

typedef unsigned short u16;
typedef unsigned int u32;
typedef __bf16 bf16x8 __attribute__((ext_vector_type(8)));
typedef float f32x4 __attribute__((ext_vector_type(4)));

#define NN_ (2048LL*2048LL)

__device__ __forceinline__ float bf2f(u16 u){
  u32 x = ((u32)u) << 16; return __builtin_bit_cast(float, x);
}
__device__ __forceinline__ u16 f2bf(float f){
  u32 x = __builtin_bit_cast(u32, f);
  u32 r = (x + 0x7fffu + ((x >> 16) & 1u)) >> 16;
  return (u16)r;
}

__device__ __forceinline__ void gload16(const u16* g, u16* l){
  __builtin_amdgcn_global_load_lds((const __attribute__((address_space(1))) u32*)g,
                                   (__attribute__((address_space(3))) u32*)l, 16, 0, 0);
}

// ---------------- prep0: softmax filters + bsum + flag zero ----------------
__global__ void k_prep0(const float* __restrict__ w1, const float* __restrict__ w2,
                        const float* __restrict__ w3, float* __restrict__ filt,
                        const float* __restrict__ bih, const float* __restrict__ bhh,
                        float* __restrict__ bsum, u32* __restrict__ flagv){
  const int i = blockIdx.x*256 + threadIdx.x;
  bsum[i] = bih[i] + bhh[i];
  flagv[i] = 0;
  if(blockIdx.x==0 && threadIdx.x < 3*C_){
    const int t = threadIdx.x;
    const int fi = t / C_, c = t % C_;
    const float* w = (fi==0) ? w1 : ((fi==1) ? w2 : w3);
    float v[E_]; float mx = -3.4e38f;
    for(int e=0;e<E_;e++){ v[e] = w[c*E_+e]; mx = fmaxf(mx, v[e]); }
    float s = 0.f;
    for(int e=0;e<E_;e++){ v[e] = expf(v[e]-mx); s += v[e]; }
    for(int e=0;e<E_;e++) filt[(fi*C_+c)*E_ + e] = v[e]/s;
  }
}

// ---------------- single-pass combine: HA (direct) + HBt + HB2t (transposed) ----------------
__global__ void k_combineAll3(const float* __restrict__ A, const float* __restrict__ filt,
                              u16* __restrict__ HA, u16* __restrict__ HBt,
                              u16* __restrict__ HB2t){
  __shared__ float te[3][32][33];
  const int ti = blockIdx.x, tj = blockIdx.y;
  const int x = threadIdx.x, y0 = threadIdx.y;
  #pragma unroll
  for(int i=0;i<4;i++){
    const int y = y0 + i*8;
    const long base = (long)(tj*32+y)*N_ + ti*32 + x;
    const float a0 = A[0*NN_+base], a1 = A[1*NN_+base], a2 = A[2*NN_+base];
    te[0][y][x]=a0; te[1][y][x]=a1; te[2][y][x]=a2;
    #pragma unroll
    for(int c=0;c<C_;c++)
      HA[c*NN_ + base] = f2bf(filt[c*E_]*a0 + filt[c*E_+1]*a1 + filt[c*E_+2]*a2);
  }
  __syncthreads();
  #pragma unroll
  for(int i=0;i<4;i++){
    const int y = y0 + i*8;
    const long ob = (long)(ti*32+y)*N_ + tj*32 + x;
    const float a0=te[0][x][y], a1=te[1][x][y], a2=te[2][x][y];
    #pragma unroll
    for(int c=0;c<C_;c++){
      HBt[c*NN_+ob]  = f2bf(filt[(C_+c)*E_]*a0   + filt[(C_+c)*E_+1]*a1   + filt[(C_+c)*E_+2]*a2);
      HB2t[c*NN_+ob] = f2bf(filt[(2*C_+c)*E_]*a0 + filt[(2*C_+c)*E_+1]*a1 + filt[(2*C_+c)*E_+2]*a2);
    }
  }
}

// ---------------- MFMA GEMM (BK=64): OUT[i][j] = sum_k A[i][k]*B[j][k] ----------------
// LDS row = 64 cols; logical chunk q of row r stored at slot q^(r&7) (pre-swizzled source).
// MODE 1: bf16 raw; 2: bf16 relu(dis[row]*acc+bias[col]); 3: f32 acc+bias[col];
// MODE 4: Gq scatter (16-batch groups); MODE 5: bf16 (acc+(row==col))*disv[col];
// MODE 6: f32 sigmoid(acc), rows < B_ only (score head)
template<int MODE>
__global__ __launch_bounds__(256) void gemm_bt(
    const u16* __restrict__ Ag, const u16* __restrict__ Bg, void* __restrict__ Cg,
    int K, int ldc, long sA, long sB, long sC,
    const float* __restrict__ disv, int sDis, const float* __restrict__ bias)
{
  __shared__ u16 At[128*64];
  __shared__ u16 Bt[128*64];
  const int tid = threadIdx.x;
  const int w = tid >> 6, l = tid & 63;
  const int z = blockIdx.z;
  const u16* Ab = Ag + (long)z*sA;
  const u16* Bb = Bg + (long)z*sB;
  const int rowBase = blockIdx.y*128;
  const int colBase = blockIdx.x*128;

  f32x4 acc[4][4];
  #pragma unroll
  for(int i=0;i<4;i++)
    #pragma unroll
    for(int j=0;j<4;j++)
      acc[i][j] = f32x4{0.f,0.f,0.f,0.f};

  const int wr = w >> 1, wc = w & 1;
  const int srow = l >> 3;                       // 0..7 within chunk
  const int scol = ((l & 7) ^ srow) << 3;        // pre-swizzled source col
  const int frow = l & 15;
  const int fkc = l >> 4;                        // 0..3

  const int nk = K >> 6;
  for(int kt=0; kt<nk; ++kt){
    const int k0 = kt << 6;
    #pragma unroll
    for(int r=0;r<4;r++){
      const int ch = w*4 + r;
      gload16(Ab + (long)(rowBase + ch*8 + srow)*K + k0 + scol, &At[ch*512]);
      gload16(Bb + (long)(colBase + ch*8 + srow)*K + k0 + scol, &Bt[ch*512]);
    }
    __syncthreads();
    #pragma unroll
    for(int ks=0; ks<2; ++ks){
      bf16x8 af[4], bfv[4];
      #pragma unroll
      for(int m=0;m<4;m++){
        const int rr = wr*64 + m*16 + frow;
        af[m] = *(const bf16x8*)&At[rr*64 + (((ks*4 + fkc) ^ (rr&7))<<3)];
      }
      #pragma unroll
      for(int n=0;n<4;n++){
        const int rr = wc*64 + n*16 + frow;
        bfv[n] = *(const bf16x8*)&Bt[rr*64 + (((ks*4 + fkc) ^ (rr&7))<<3)];
      }
      #pragma unroll
      for(int m=0;m<4;m++)
        #pragma unroll
        for(int n=0;n<4;n++)
          acc[m][n] = __builtin_amdgcn_mfma_f32_16x16x32_bf16(af[m], bfv[n], acc[m][n], 0, 0, 0);
    }
    __syncthreads();
  }

  #pragma unroll
  for(int m=0;m<4;m++){
    const int row0 = rowBase + wr*64 + m*16 + (l>>4)*4;
    #pragma unroll
    for(int n=0;n<4;n++){
      const int col = colBase + wc*64 + n*16 + (l&15);
      #pragma unroll
      for(int r=0;r<4;r++){
        const float v = acc[m][n][r];
        if(MODE==1){
          ((u16*)Cg)[z*sC + (long)(row0+r)*ldc + col] = f2bf(v);
        } else if(MODE==2){
          float o = disv[z*(long)sDis + row0 + r]*v + bias[col];
          o = o > 0.f ? o : 0.f;
          ((u16*)Cg)[z*sC + (long)(row0+r)*ldc + col] = f2bf(o);
        } else if(MODE==3){
          ((float*)Cg)[z*sC + (long)(row0+r)*ldc + col] = v + bias[col];
        } else if(MODE==4){
          const int row = row0 + r;
          if(row < BT_){
            const int bb = row/50, tt = row - bb*50;
            const int gate = col >> 9, ugg = col & 511;
            ((float*)Cg)[((((long)tt*4 + (bb>>4))*512 + ugg)*16 + (bb&15))*4 + gate] = v + bias[col];
          }
        } else if(MODE==5){
          const int row = row0 + r;
          const float o = (v + (row==col ? 1.f : 0.f)) * disv[z*(long)sDis + col];
          ((u16*)Cg)[z*sC + (long)row*ldc + col] = f2bf(o);
        } else if(MODE==6){
          const int row = row0 + r;
          if(row < B_)
            ((float*)Cg)[(long)row*ldc + col] = 1.f/(1.f + expf(-v));
        }
      }
    }
  }
}

// ---------------- column-degree partial sums ----------------
__global__ void k_degpart(const u16* __restrict__ H, float* __restrict__ partial){
  const int c = blockIdx.z;
  const int col = blockIdx.x*256 + threadIdx.x;
  const int r0 = blockIdx.y*128;
  const u16* Hc = H + c*NN_;
  float s = 0.f;
  #pragma unroll 4
  for(int r=0;r<128;r++) s += bf2f(Hc[(long)(r0+r)*N_ + col]);
  partial[((long)c*16 + blockIdx.y)*N_ + col] = s;
}

// ---------------- dinv[c][m] = 1/(colsum - diag), guarded ----------------
__global__ void k_dinv(const u16* __restrict__ H, const float* __restrict__ partial,
                       float* __restrict__ dinvb){
  const int i = blockIdx.x*256 + threadIdx.x;
  const int c = i >> 11, m = i & (N_-1);
  float s = 0.f;
  #pragma unroll
  for(int p=0;p<16;p++) s += partial[((long)c*16 + p)*N_ + m];
  s -= bf2f(H[c*NN_ + (long)m*N_ + m]);
  dinvb[i] = s > 0.f ? 1.f/s : 0.f;
}

// ---------------- H[j][i] = (j==i) ? 0 : H*dinv[i] ----------------
__global__ void k_colscale(u16* __restrict__ H, const float* __restrict__ dinvb){
  const long i = (long)blockIdx.x*256 + threadIdx.x;
  const int c = blockIdx.y;
  const int j = (int)(i >> 11), ii = (int)(i & (N_-1));
  const long idx = c*NN_ + i;
  const float v = (j==ii) ? 0.f : bf2f(H[idx])*dinvb[c*N_ + ii];
  H[idx] = f2bf(v);
}

// ---------------- dis[c][j] = rsqrt(1 + sum_k HB2t[c][j][k]*mask[k]) ----------------
__global__ void k_dis(const u16* __restrict__ HB2t, const float* __restrict__ dinvb,
                      float* __restrict__ disv){
  const int c = blockIdx.y, j = blockIdx.x;
  const u16* r = HB2t + (c*(long)N_ + j)*N_;
  const float* dv = dinvb + c*N_;
  float s = 0.f;
  for(int i=threadIdx.x;i<N_;i+=256)
    if(dv[i] > 0.f) s += bf2f(r[i]);
  __shared__ float red[256];
  red[threadIdx.x] = s;
  __syncthreads();
  for(int st=128; st>0; st>>=1){
    if(threadIdx.x < st) red[threadIdx.x] += red[threadIdx.x+st];
    __syncthreads();
  }
  if(threadIdx.x==0){
    const float deg = red[0] + 1.f;
    disv[c*N_ + j] = deg > 0.f ? rsqrtf(deg) : 0.f;
  }
}

// ---------------- 2-in-1 transpose f32 -> bf16 ----------------
__global__ void k_transpose3(const float* __restrict__ gcnW, u16* __restrict__ Wt,
                             const float* __restrict__ lin1W, u16* __restrict__ l1Wt){
  const float* in; u16* out; int R, Cc;
  if(blockIdx.z==0){ in=gcnW;  out=Wt;   R=WIN_;     Cc=WOUT_; }
  else { in=lin1W; out=l1Wt; R=C_*WOUT_; Cc=WOUT_; }
  const int ti = blockIdx.x, tj = blockIdx.y;
  if(ti >= (Cc>>5) || tj >= (R>>5)) return;
  __shared__ float tt[32][33];
  const int x = threadIdx.x, y0 = threadIdx.y;
  #pragma unroll
  for(int i=0;i<4;i++){
    const int y = y0 + i*8;
    tt[y][x] = in[(long)(tj*32+y)*Cc + ti*32 + x];
  }
  __syncthreads();
  #pragma unroll
  for(int i=0;i<4;i++){
    const int y = y0 + i*8;
    out[(long)(ti*32+y)*R + tj*32 + x] = f2bf(tt[x][y]);
  }
}

// ---------------- triple cast f32 -> bf16 (X, Wih, scoreW) ----------------
__global__ void k_cast3(const float* __restrict__ X, u16* __restrict__ Xbf,
                        const float* __restrict__ Wih, u16* __restrict__ Wihbf,
                        const float* __restrict__ scoreW, u16* __restrict__ sWbf){
  const long i = (long)blockIdx.x*256 + threadIdx.x;
  if(i < (long)N_*WIN_) Xbf[i] = f2bf(X[i]);
  else if(i < (long)N_*WIN_ + 4*U_*WOUT_){
    const long j = i - (long)N_*WIN_; Wihbf[j] = f2bf(Wih[j]);
  } else {
    const long j = i - (long)N_*WIN_ - 4*U_*WOUT_; sWbf[j] = f2bf(scoreW[j]);
  }
}

// ---------------- basket max-pool (grid 52x64; t>=50 writes pad zeros) ----------------
__global__ void k_pool(const float* __restrict__ seqs, const float* __restrict__ X_,
                       u16* __restrict__ bs){
  const int t = blockIdx.x, b = blockIdx.y;
  const int f = threadIdx.x;
  if(t >= T_){
    bs[(long)(BT_ + b*2 + (t-T_))*WOUT_ + f] = 0;
    return;
  }
  const float* mask = seqs + ((long)b*T_ + t)*N_;
  __shared__ int list[N_];
  __shared__ int cnt;
  if(f==0) cnt = 0;
  __syncthreads();
  for(int n0=f; n0<N_; n0+=256){
    if(mask[n0] > 0.f){
      int p = atomicAdd(&cnt, 1);
      list[p] = n0;
    }
  }
  __syncthreads();
  const int m = cnt;
  float mx = -3.4e38f;
  for(int i=0;i<m;i++)
    mx = fmaxf(mx, X_[(long)list[i]*WOUT_ + f]);
  bs[((long)b*T_ + t)*WOUT_ + f] = f2bf(m>0 ? mx : 0.f);
}

// ---------------- pack Whh for register-resident A-frags (r8 layout) ----------------
__global__ void k_packWhh3(const float* __restrict__ Whh, u16* __restrict__ P){
  const long idx = (long)blockIdx.x*256 + threadIdx.x;
  const int e  = (int)(idx & 7);
  const int kk = (int)((idx >> 3) & 15);
  const int l  = (int)((idx >> 7) & 63);
  const int w  = (int)((idx >> 13) & 7);
  const int s  = (int)(idx >> 16);
  const int lr = w*16 + (l & 15);
  const int gam = lr & 3, ui = lr >> 2;
  const int grow = gam*512 + s*32 + ui;
  const int k = kk*32 + (l >> 4)*8 + e;
  P[idx] = f2bf(Whh[(long)grow*512 + k]);
}

// ---------------- Hglob init: per-group [16 b][512 u] pre-swizzled ----------------
__global__ void k_hinit(const float* __restrict__ h0, u16* __restrict__ Hglob){
  const int idx = blockIdx.x*256 + threadIdx.x;
  const int b = idx >> 9, u = idx & 511;
  const int grp = b >> 4, bl = b & 15;
  Hglob[grp*16384 + (bl << 9) + (u ^ ((bl & 7) << 3))] = f2bf(h0[idx]);
}

// ---------------- persistent LSTM (r8-proven): 4 XCD-affine groups x 16 blocks ----------------
__global__ __launch_bounds__(512) void k_lstm_all(
    const u16* __restrict__ WhhP, const float* __restrict__ Gq,
    const float* __restrict__ c0v, const int* __restrict__ seqlen,
    u16* __restrict__ Hglob, u32* __restrict__ flagv, u16* __restrict__ act)
{
  __shared__ u16 Hl[16*512];
  const int tid = threadIdx.x;
  const int w = tid >> 6, l = tid & 63;
  const int grp = blockIdx.x & 3, s = blockIdx.x >> 2;
  const int fr = l & 15, hi = l >> 4;

  bf16x8 wreg[16];
  const u16* wp = WhhP + (((long)s*8 + w)*64 + l)*128;
  #pragma unroll
  for(int kk=0; kk<16; ++kk)
    wreg[kk] = *(const bf16x8*)&wp[kk*8];

  const int ug = s*32 + w*4 + hi;
  const int bl = fr;
  const int bg = grp*16 + bl;
  float cst = c0v[bg*U_ + ug];
  const int sl = seqlen[bg] - 1;
  u16* Hbase = Hglob + grp*16384;
  const int hswz = (bl & 7) << 3;
  const int fi = (grp*16 + fr)*32;
  const long gqbase = (((long)grp*512 + ug)*16 + bl)*4;
  float4 gq_nxt = *(const float4*)&Gq[gqbase];

  for(int t=0; t<T_; ++t){
    const float4 gq = gq_nxt;
    const u16* Hin = Hbase + (t & 1)*8192;
    #pragma unroll
    for(int r=0; r<2; ++r)
      gload16(Hin + (r*8 + w)*512 + l*8, &Hl[(r*8 + w)*512]);
    __syncthreads();

    f32x4 acc = f32x4{0.f,0.f,0.f,0.f};
    #pragma unroll
    for(int kk=0; kk<16; ++kk){
      const int ke = kk*32 + hi*8;
      bf16x8 bb = *(const bf16x8*)&Hl[(bl << 9) + (ke ^ hswz)];
      acc = __builtin_amdgcn_mfma_f32_16x16x32_bf16(wreg[kk], bb, acc, 0, 0, 0);
    }

    if(t+1 < T_)
      gq_nxt = *(const float4*)&Gq[(long)(t+1)*(4*2048*16) + gqbase];

    const float a0 = acc[0] + gq.x;
    const float a1 = acc[1] + gq.y;
    const float a2 = acc[2] + gq.z;
    const float a3 = acc[3] + gq.w;
    const float ig = 1.f/(1.f + expf(-a0));
    const float fg = 1.f/(1.f + expf(-a1));
    const float gg = tanhf(a2);
    const float og = 1.f/(1.f + expf(-a3));
    cst = fg*cst + ig*gg;
    const float h = og*tanhf(cst);
    u16* Hout = Hbase + ((t+1) & 1)*8192;
    Hout[(bl << 9) + (ug ^ hswz)] = f2bf(h);
    if(sl == t) act[bg*U_ + ug] = f2bf(h);

    if(t == T_-1) break;
    __syncthreads();
    if(tid == 0)
      __hip_atomic_store(&flagv[(grp*16 + s)*32], (u32)(t+1),
                         __ATOMIC_RELEASE, __HIP_MEMORY_SCOPE_AGENT);
    if(w == 0){
      while(__hip_atomic_load(&flagv[fi], __ATOMIC_ACQUIRE,
                              __HIP_MEMORY_SCOPE_AGENT) <= (u32)t){
        __builtin_amdgcn_s_sleep(1);
      }
    }
    __syncthreads();
  }
}

extern "C" void kernel_launch(void* const* d_in, const int* in_sizes, int n_in,
                              void* d_out, int out_size, void* d_ws, size_t ws_size,
                              hipStream_t stream){
  (void)in_sizes; (void)n_in; (void)out_size; (void)ws_size;
  const float* A      = (const float*)d_in[0];
  const float* X      = (const float*)d_in[1];
  const float* seqs   = (const float*)d_in[2];
  const int*   seqlen = (const int*)d_in[3];
  const float* h0     = (const float*)d_in[4];
  const float* c0     = (const float*)d_in[5];
  const float* gtw1   = (const float*)d_in[6];
  const float* gtw2   = (const float*)d_in[7];
  const float* gtw3   = (const float*)d_in[8];
  const float* gcnW   = (const float*)d_in[9];
  const float* gcnB   = (const float*)d_in[10];
  const float* lin1W  = (const float*)d_in[11];
  const float* lin1B  = (const float*)d_in[12];
  const float* Wih    = (const float*)d_in[13];
  const float* Whh    = (const float*)d_in[14];
  const float* bihp   = (const float*)d_in[15];
  const float* bhhp   = (const float*)d_in[16];
  const float* scoreW = (const float*)d_in[17];

  char* ws = (char*)d_ws;
  u16* buf0 = (u16*)(ws + 0);
  u16* buf1 = (u16*)(ws + 16777216);
  u16* buf2 = (u16*)(ws + 33554432);
  char* S0  = ws + 50331648;
  float* filt  = (float*)(S0 + 0);
  float* disv  = (float*)(S0 + 1024);
  u16*  Wt     = (u16*) (S0 + 17408);
  u16*  XWt    = (u16*) (S0 + 148480);
  u16*  catb   = (u16*) (S0 + 1197056);
  u16*  l1Wt   = (u16*) (S0 + 3294208);
  float* Xo    = (float*)(S0 + 3556352);
  u16*  bs     = (u16*) (S0 + 5653504);
  u16*  act    = (u16*) (S0 + 7357440);    // 128x512 bf16 (rows 64..127 = pad)
  u16*  sWbf   = (u16*) (S0 + 7488512);    // scoreW bf16, 2048x512
  u16*  WhhB   = (u16*) (S0 + 9585664);
  u16*  Xbf    = (u16*) (S0 + 11682816);
  u16*  Wihbf  = (u16*) (S0 + 12731392);
  float* bsum  = (float*)(S0 + 13779968);
  u16*  Hglob  = (u16*) (S0 + 13788160);   // 4 grp x 16384 u16 = 128 KB
  u32*  flagv  = (u32*) (S0 + 13919232);   // 2048 u32
  float* degp  = (float*)(S0 + 14050304);
  float* dinvb = (float*)(S0 + 14312448);  // S0 ends at 14328832
  u16* buf3 = (u16*)(ws + 64660480);       // 16 MiB (total 77.66 MB < 78.79 MB r1-proven)
  u16* HA   = buf0;
  u16* HBt  = buf1;
  u16* Hb   = buf2;
  u16* HB2t = buf3;
  u16* Pd   = buf1;
  float* Gq = (float*)ws;   // 26.2 MiB over buf0+buf1 (dead by then)

  k_prep0<<<dim3(8), 256, 0, stream>>>(gtw1, gtw2, gtw3, filt, bihp, bhhp, bsum, flagv);
  k_combineAll3<<<dim3(N_/32, N_/32), dim3(32,8), 0, stream>>>(A, filt, HA, HBt, HB2t);
  k_transpose3<<<dim3(16, 64, 2), dim3(32,8), 0, stream>>>(gcnW, Wt, lin1W, l1Wt);
  k_cast3<<<dim3(8192), 256, 0, stream>>>(X, Xbf, Wih, Wihbf, scoreW, sWbf);
  gemm_bt<1><<<dim3(16,16,C_), 256, 0, stream>>>(HA, HBt, Hb, N_, N_, NN_, NN_, NN_, nullptr, 0, nullptr);
  k_degpart<<<dim3(8, 16, C_), 256, 0, stream>>>(Hb, degp);
  k_dinv<<<dim3(16), 256, 0, stream>>>(Hb, degp, dinvb);
  k_colscale<<<dim3(NN_/256, C_), 256, 0, stream>>>(Hb, dinvb);
  k_dis<<<dim3(N_, C_), 256, 0, stream>>>(HB2t, dinvb, disv);
  gemm_bt<5><<<dim3(16,16,C_), 256, 0, stream>>>(HB2t, Hb, Pd, N_, N_, NN_, NN_, NN_, disv, N_, nullptr);
  gemm_bt<1><<<dim3(N_/128, WOUT_/128, 1), 256, 0, stream>>>(Wt, Xbf, XWt, WIN_, N_, 0, 0, 0, nullptr, 0, nullptr);
  gemm_bt<2><<<dim3(WOUT_/128, N_/128, C_), 256, 0, stream>>>(Pd, XWt, catb, N_, C_*WOUT_, NN_, 0, WOUT_, disv, N_, gcnB);
  gemm_bt<3><<<dim3(WOUT_/128, N_/128, 1), 256, 0, stream>>>(catb, l1Wt, Xo, C_*WOUT_, WOUT_, 0, 0, 0, nullptr, 0, lin1B);
  k_pool<<<dim3(52, B_), 256, 0, stream>>>(seqs, Xo, bs);
  gemm_bt<4><<<dim3((4*U_)/128, BTP_/128, 1), 256, 0, stream>>>(bs, Wihbf, Gq, WOUT_, 0, 0, 0, 0, nullptr, 0, bsum);
  k_packWhh3<<<dim3(4096), 256, 0, stream>>>(Whh, WhhB);
  k_hinit<<<dim3(128), 256, 0, stream>>>(h0, Hglob);
  k_lstm_all<<<dim3(64), 512, 0, stream>>>(WhhB, Gq, c0, seqlen, Hglob, flagv, act);
  // out = sigmoid(act @ scoreW^T) via MFMA (rows >= 64 discarded)
  gemm_bt<6><<<dim3(N_/128, 1, 1), 256, 0, stream>>>(act, sWbf, (float*)d_out, U_, N_, 0, 0, 0, nullptr, 0, nullptr);
}

// Round 14
// 503.987 us; speedup vs baseline: 6.6244x; 1.0344x over previous
//
#include <hip/hip_runtime.h>
#include <stdint.h>

#define E_ 3
#define C_ 2
#define N_ 2048
#define B_ 64
#define T_ 50
#define WIN_ 256
#define WOUT_ 256
#define U_ 512
#define BT_ (B_*T_)
#define BTP_ 3328

typedef unsigned short u16;
typedef unsigned int u32;
typedef __bf16 bf16x8 __attribute__((ext_vector_type(8)));
typedef float f32x4 __attribute__((ext_vector_type(4)));

#define NN_ (2048LL*2048LL)

__device__ __forceinline__ float bf2f(u16 u){
  u32 x = ((u32)u) << 16; return __builtin_bit_cast(float, x);
}
__device__ __forceinline__ u16 f2bf(float f){
  u32 x = __builtin_bit_cast(u32, f);
  u32 r = (x + 0x7fffu + ((x >> 16) & 1u)) >> 16;
  return (u16)r;
}

__device__ __forceinline__ void gload16(const u16* g, u16* l){
  __builtin_amdgcn_global_load_lds((const __attribute__((address_space(1))) u32*)g,
                                   (__attribute__((address_space(3))) u32*)l, 16, 0, 0);
}

// ---------------- prep0: softmax filters + bsum + flag zero ----------------
__global__ void k_prep0(const float* __restrict__ w1, const float* __restrict__ w2,
                        const float* __restrict__ w3, float* __restrict__ filt,
                        const float* __restrict__ bih, const float* __restrict__ bhh,
                        float* __restrict__ bsum, u32* __restrict__ flagv){
  const int i = blockIdx.x*256 + threadIdx.x;
  bsum[i] = bih[i] + bhh[i];
  flagv[i] = 0;
  if(blockIdx.x==0 && threadIdx.x < 3*C_){
    const int t = threadIdx.x;
    const int fi = t / C_, c = t % C_;
    const float* w = (fi==0) ? w1 : ((fi==1) ? w2 : w3);
    float v[E_]; float mx = -3.4e38f;
    for(int e=0;e<E_;e++){ v[e] = w[c*E_+e]; mx = fmaxf(mx, v[e]); }
    float s = 0.f;
    for(int e=0;e<E_;e++){ v[e] = expf(v[e]-mx); s += v[e]; }
    for(int e=0;e<E_;e++) filt[(fi*C_+c)*E_ + e] = v[e]/s;
  }
}

// ---------------- single-pass combine: HA (direct) + HBt + HB2t (transposed) ----------------
__global__ void k_combineAll3(const float* __restrict__ A, const float* __restrict__ filt,
                              u16* __restrict__ HA, u16* __restrict__ HBt,
                              u16* __restrict__ HB2t){
  __shared__ float te[3][32][33];
  const int ti = blockIdx.x, tj = blockIdx.y;
  const int x = threadIdx.x, y0 = threadIdx.y;
  #pragma unroll
  for(int i=0;i<4;i++){
    const int y = y0 + i*8;
    const long base = (long)(tj*32+y)*N_ + ti*32 + x;
    const float a0 = A[0*NN_+base], a1 = A[1*NN_+base], a2 = A[2*NN_+base];
    te[0][y][x]=a0; te[1][y][x]=a1; te[2][y][x]=a2;
    #pragma unroll
    for(int c=0;c<C_;c++)
      HA[c*NN_ + base] = f2bf(filt[c*E_]*a0 + filt[c*E_+1]*a1 + filt[c*E_+2]*a2);
  }
  __syncthreads();
  #pragma unroll
  for(int i=0;i<4;i++){
    const int y = y0 + i*8;
    const long ob = (long)(ti*32+y)*N_ + tj*32 + x;
    const float a0=te[0][x][y], a1=te[1][x][y], a2=te[2][x][y];
    #pragma unroll
    for(int c=0;c<C_;c++){
      HBt[c*NN_+ob]  = f2bf(filt[(C_+c)*E_]*a0   + filt[(C_+c)*E_+1]*a1   + filt[(C_+c)*E_+2]*a2);
      HB2t[c*NN_+ob] = f2bf(filt[(2*C_+c)*E_]*a0 + filt[(2*C_+c)*E_+1]*a1 + filt[(2*C_+c)*E_+2]*a2);
    }
  }
}

// ---------------- MFMA GEMM (BK=64, double-buffered, prefetch-overlap) ----------------
// OUT[i][j] = sum_k A[i][k]*B[j][k]; LDS chunk q of row r at slot q^(r&7) (pre-swizzled src).
// MODE 1: bf16 raw; 2: bf16 relu(dis[row]*acc+bias[col]); 3: f32 acc+bias[col];
// MODE 4: Gq scatter (16-batch groups); MODE 5: bf16 (acc+(row==col))*disv[col];
// MODE 6: f32 sigmoid(acc), rows < B_ only (score head)
template<int MODE>
__global__ __launch_bounds__(256) void gemm_bt(
    const u16* __restrict__ Ag, const u16* __restrict__ Bg, void* __restrict__ Cg,
    int K, int ldc, long sA, long sB, long sC,
    const float* __restrict__ disv, int sDis, const float* __restrict__ bias)
{
  __shared__ u16 At[2][128*64];
  __shared__ u16 Bt[2][128*64];
  const int tid = threadIdx.x;
  const int w = tid >> 6, l = tid & 63;
  const int z = blockIdx.z;
  const u16* Ab = Ag + (long)z*sA;
  const u16* Bb = Bg + (long)z*sB;
  const int rowBase = blockIdx.y*128;
  const int colBase = blockIdx.x*128;

  f32x4 acc[4][4];
  #pragma unroll
  for(int i=0;i<4;i++)
    #pragma unroll
    for(int j=0;j<4;j++)
      acc[i][j] = f32x4{0.f,0.f,0.f,0.f};

  const int wr = w >> 1, wc = w & 1;
  const int srow = l >> 3;                       // 0..7 within chunk
  const int scol = ((l & 7) ^ srow) << 3;        // pre-swizzled source col
  const int frow = l & 15;
  const int fkc = l >> 4;                        // 0..3

  const int nk = K >> 6;
  // prologue: stage tile 0 into buffer 0
  #pragma unroll
  for(int r=0;r<4;r++){
    const int ch = w*4 + r;
    gload16(Ab + (long)(rowBase + ch*8 + srow)*K + scol, &At[0][ch*512]);
    gload16(Bb + (long)(colBase + ch*8 + srow)*K + scol, &Bt[0][ch*512]);
  }
  __syncthreads();                               // tile 0 resident

  for(int kt=0; kt<nk; ++kt){
    const int cur = kt & 1;
    // issue next tile's staging BEFORE compute — overlaps with MFMA below
    if(kt+1 < nk){
      const int k0 = (kt+1) << 6;
      #pragma unroll
      for(int r=0;r<4;r++){
        const int ch = w*4 + r;
        gload16(Ab + (long)(rowBase + ch*8 + srow)*K + k0 + scol, &At[cur^1][ch*512]);
        gload16(Bb + (long)(colBase + ch*8 + srow)*K + k0 + scol, &Bt[cur^1][ch*512]);
      }
    }
    #pragma unroll
    for(int ks=0; ks<2; ++ks){
      bf16x8 af[4], bfv[4];
      #pragma unroll
      for(int m=0;m<4;m++){
        const int rr = wr*64 + m*16 + frow;
        af[m] = *(const bf16x8*)&At[cur][rr*64 + (((ks*4 + fkc) ^ (rr&7))<<3)];
      }
      #pragma unroll
      for(int n=0;n<4;n++){
        const int rr = wc*64 + n*16 + frow;
        bfv[n] = *(const bf16x8*)&Bt[cur][rr*64 + (((ks*4 + fkc) ^ (rr&7))<<3)];
      }
      #pragma unroll
      for(int m=0;m<4;m++)
        #pragma unroll
        for(int n=0;n<4;n++)
          acc[m][n] = __builtin_amdgcn_mfma_f32_16x16x32_bf16(af[m], bfv[n], acc[m][n], 0, 0, 0);
    }
    if(kt+1 < nk) __syncthreads();   // drains prefetch (mostly done) + guards LDS reuse
  }

  #pragma unroll
  for(int m=0;m<4;m++){
    const int row0 = rowBase + wr*64 + m*16 + (l>>4)*4;
    #pragma unroll
    for(int n=0;n<4;n++){
      const int col = colBase + wc*64 + n*16 + (l&15);
      #pragma unroll
      for(int r=0;r<4;r++){
        const float v = acc[m][n][r];
        if(MODE==1){
          ((u16*)Cg)[z*sC + (long)(row0+r)*ldc + col] = f2bf(v);
        } else if(MODE==2){
          float o = disv[z*(long)sDis + row0 + r]*v + bias[col];
          o = o > 0.f ? o : 0.f;
          ((u16*)Cg)[z*sC + (long)(row0+r)*ldc + col] = f2bf(o);
        } else if(MODE==3){
          ((float*)Cg)[z*sC + (long)(row0+r)*ldc + col] = v + bias[col];
        } else if(MODE==4){
          const int row = row0 + r;
          if(row < BT_){
            const int bb = row/50, tt = row - bb*50;
            const int gate = col >> 9, ugg = col & 511;
            ((float*)Cg)[((((long)tt*4 + (bb>>4))*512 + ugg)*16 + (bb&15))*4 + gate] = v + bias[col];
          }
        } else if(MODE==5){
          const int row = row0 + r;
          const float o = (v + (row==col ? 1.f : 0.f)) * disv[z*(long)sDis + col];
          ((u16*)Cg)[z*sC + (long)row*ldc + col] = f2bf(o);
        } else if(MODE==6){
          const int row = row0 + r;
          if(row < B_)
            ((float*)Cg)[(long)row*ldc + col] = 1.f/(1.f + expf(-v));
        }
      }
    }
  }
}

// ---------------- column-degree partial sums ----------------
__global__ void k_degpart(const u16* __restrict__ H, float* __restrict__ partial){
  const int c = blockIdx.z;
  const int col = blockIdx.x*256 + threadIdx.x;
  const int r0 = blockIdx.y*128;
  const u16* Hc = H + c*NN_;
  float s = 0.f;
  #pragma unroll 4
  for(int r=0;r<128;r++) s += bf2f(Hc[(long)(r0+r)*N_ + col]);
  partial[((long)c*16 + blockIdx.y)*N_ + col] = s;
}

// ---------------- dinv[c][m] = 1/(colsum - diag), guarded ----------------
__global__ void k_dinv(const u16* __restrict__ H, const float* __restrict__ partial,
                       float* __restrict__ dinvb){
  const int i = blockIdx.x*256 + threadIdx.x;
  const int c = i >> 11, m = i & (N_-1);
  float s = 0.f;
  #pragma unroll
  for(int p=0;p<16;p++) s += partial[((long)c*16 + p)*N_ + m];
  s -= bf2f(H[c*NN_ + (long)m*N_ + m]);
  dinvb[i] = s > 0.f ? 1.f/s : 0.f;
}

// ---------------- H[j][i] = (j==i) ? 0 : H*dinv[i] ----------------
__global__ void k_colscale(u16* __restrict__ H, const float* __restrict__ dinvb){
  const long i = (long)blockIdx.x*256 + threadIdx.x;
  const int c = blockIdx.y;
  const int j = (int)(i >> 11), ii = (int)(i & (N_-1));
  const long idx = c*NN_ + i;
  const float v = (j==ii) ? 0.f : bf2f(H[idx])*dinvb[c*N_ + ii];
  H[idx] = f2bf(v);
}

// ---------------- dis[c][j] = rsqrt(1 + sum_k HB2t[c][j][k]*mask[k]) ----------------
__global__ void k_dis(const u16* __restrict__ HB2t, const float* __restrict__ dinvb,
                      float* __restrict__ disv){
  const int c = blockIdx.y, j = blockIdx.x;
  const u16* r = HB2t + (c*(long)N_ + j)*N_;
  const float* dv = dinvb + c*N_;
  float s = 0.f;
  for(int i=threadIdx.x;i<N_;i+=256)
    if(dv[i] > 0.f) s += bf2f(r[i]);
  __shared__ float red[256];
  red[threadIdx.x] = s;
  __syncthreads();
  for(int st=128; st>0; st>>=1){
    if(threadIdx.x < st) red[threadIdx.x] += red[threadIdx.x+st];
    __syncthreads();
  }
  if(threadIdx.x==0){
    const float deg = red[0] + 1.f;
    disv[c*N_ + j] = deg > 0.f ? rsqrtf(deg) : 0.f;
  }
}

// ---------------- 2-in-1 transpose f32 -> bf16 ----------------
__global__ void k_transpose3(const float* __restrict__ gcnW, u16* __restrict__ Wt,
                             const float* __restrict__ lin1W, u16* __restrict__ l1Wt){
  const float* in; u16* out; int R, Cc;
  if(blockIdx.z==0){ in=gcnW;  out=Wt;   R=WIN_;     Cc=WOUT_; }
  else { in=lin1W; out=l1Wt; R=C_*WOUT_; Cc=WOUT_; }
  const int ti = blockIdx.x, tj = blockIdx.y;
  if(ti >= (Cc>>5) || tj >= (R>>5)) return;
  __shared__ float tt[32][33];
  const int x = threadIdx.x, y0 = threadIdx.y;
  #pragma unroll
  for(int i=0;i<4;i++){
    const int y = y0 + i*8;
    tt[y][x] = in[(long)(tj*32+y)*Cc + ti*32 + x];
  }
  __syncthreads();
  #pragma unroll
  for(int i=0;i<4;i++){
    const int y = y0 + i*8;
    out[(long)(ti*32+y)*R + tj*32 + x] = f2bf(tt[x][y]);
  }
}

// ---------------- triple cast f32 -> bf16 (X, Wih, scoreW) ----------------
__global__ void k_cast3(const float* __restrict__ X, u16* __restrict__ Xbf,
                        const float* __restrict__ Wih, u16* __restrict__ Wihbf,
                        const float* __restrict__ scoreW, u16* __restrict__ sWbf){
  const long i = (long)blockIdx.x*256 + threadIdx.x;
  if(i < (long)N_*WIN_) Xbf[i] = f2bf(X[i]);
  else if(i < (long)N_*WIN_ + 4*U_*WOUT_){
    const long j = i - (long)N_*WIN_; Wihbf[j] = f2bf(Wih[j]);
  } else {
    const long j = i - (long)N_*WIN_ - 4*U_*WOUT_; sWbf[j] = f2bf(scoreW[j]);
  }
}

// ---------------- basket max-pool (grid 52x64; t>=50 writes pad zeros) ----------------
__global__ void k_pool(const float* __restrict__ seqs, const float* __restrict__ X_,
                       u16* __restrict__ bs){
  const int t = blockIdx.x, b = blockIdx.y;
  const int f = threadIdx.x;
  if(t >= T_){
    bs[(long)(BT_ + b*2 + (t-T_))*WOUT_ + f] = 0;
    return;
  }
  const float* mask = seqs + ((long)b*T_ + t)*N_;
  __shared__ int list[N_];
  __shared__ int cnt;
  if(f==0) cnt = 0;
  __syncthreads();
  for(int n0=f; n0<N_; n0+=256){
    if(mask[n0] > 0.f){
      int p = atomicAdd(&cnt, 1);
      list[p] = n0;
    }
  }
  __syncthreads();
  const int m = cnt;
  float mx = -3.4e38f;
  for(int i=0;i<m;i++)
    mx = fmaxf(mx, X_[(long)list[i]*WOUT_ + f]);
  bs[((long)b*T_ + t)*WOUT_ + f] = f2bf(m>0 ? mx : 0.f);
}

// ---------------- pack Whh (r8 layout) + fused Hglob init ----------------
__global__ void k_packWhh3(const float* __restrict__ Whh, u16* __restrict__ P,
                           const float* __restrict__ h0, u16* __restrict__ Hglob){
  const long idx = (long)blockIdx.x*256 + threadIdx.x;
  const int e  = (int)(idx & 7);
  const int kk = (int)((idx >> 3) & 15);
  const int l  = (int)((idx >> 7) & 63);
  const int w  = (int)((idx >> 13) & 7);
  const int s  = (int)(idx >> 16);
  const int lr = w*16 + (l & 15);
  const int gam = lr & 3, ui = lr >> 2;
  const int grow = gam*512 + s*32 + ui;
  const int k = kk*32 + (l >> 4)*8 + e;
  P[idx] = f2bf(Whh[(long)grow*512 + k]);
  if(idx < 32768){
    const int b = (int)(idx >> 9), u = (int)(idx & 511);
    const int grp = b >> 4, bl = b & 15;
    Hglob[grp*16384 + (bl << 9) + (u ^ ((bl & 7) << 3))] = f2bf(h0[idx]);
  }
}

// ---------------- persistent LSTM (r8-proven): 4 XCD-affine groups x 16 blocks ----------------
__global__ __launch_bounds__(512) void k_lstm_all(
    const u16* __restrict__ WhhP, const float* __restrict__ Gq,
    const float* __restrict__ c0v, const int* __restrict__ seqlen,
    u16* __restrict__ Hglob, u32* __restrict__ flagv, u16* __restrict__ act)
{
  __shared__ u16 Hl[16*512];
  const int tid = threadIdx.x;
  const int w = tid >> 6, l = tid & 63;
  const int grp = blockIdx.x & 3, s = blockIdx.x >> 2;
  const int fr = l & 15, hi = l >> 4;

  bf16x8 wreg[16];
  const u16* wp = WhhP + (((long)s*8 + w)*64 + l)*128;
  #pragma unroll
  for(int kk=0; kk<16; ++kk)
    wreg[kk] = *(const bf16x8*)&wp[kk*8];

  const int ug = s*32 + w*4 + hi;
  const int bl = fr;
  const int bg = grp*16 + bl;
  float cst = c0v[bg*U_ + ug];
  const int sl = seqlen[bg] - 1;
  u16* Hbase = Hglob + grp*16384;
  const int hswz = (bl & 7) << 3;
  const int fi = (grp*16 + fr)*32;
  const long gqbase = (((long)grp*512 + ug)*16 + bl)*4;
  float4 gq_nxt = *(const float4*)&Gq[gqbase];

  for(int t=0; t<T_; ++t){
    const float4 gq = gq_nxt;
    const u16* Hin = Hbase + (t & 1)*8192;
    #pragma unroll
    for(int r=0; r<2; ++r)
      gload16(Hin + (r*8 + w)*512 + l*8, &Hl[(r*8 + w)*512]);
    __syncthreads();

    f32x4 acc = f32x4{0.f,0.f,0.f,0.f};
    #pragma unroll
    for(int kk=0; kk<16; ++kk){
      const int ke = kk*32 + hi*8;
      bf16x8 bb = *(const bf16x8*)&Hl[(bl << 9) + (ke ^ hswz)];
      acc = __builtin_amdgcn_mfma_f32_16x16x32_bf16(wreg[kk], bb, acc, 0, 0, 0);
    }

    if(t+1 < T_)
      gq_nxt = *(const float4*)&Gq[(long)(t+1)*(4*2048*16) + gqbase];

    const float a0 = acc[0] + gq.x;
    const float a1 = acc[1] + gq.y;
    const float a2 = acc[2] + gq.z;
    const float a3 = acc[3] + gq.w;
    const float ig = 1.f/(1.f + expf(-a0));
    const float fg = 1.f/(1.f + expf(-a1));
    const float gg = tanhf(a2);
    const float og = 1.f/(1.f + expf(-a3));
    cst = fg*cst + ig*gg;
    const float h = og*tanhf(cst);
    u16* Hout = Hbase + ((t+1) & 1)*8192;
    Hout[(bl << 9) + (ug ^ hswz)] = f2bf(h);
    if(sl == t) act[bg*U_ + ug] = f2bf(h);

    if(t == T_-1) break;
    __syncthreads();
    if(tid == 0)
      __hip_atomic_store(&flagv[(grp*16 + s)*32], (u32)(t+1),
                         __ATOMIC_RELEASE, __HIP_MEMORY_SCOPE_AGENT);
    if(w == 0){
      while(__hip_atomic_load(&flagv[fi], __ATOMIC_ACQUIRE,
                              __HIP_MEMORY_SCOPE_AGENT) <= (u32)t){
        __builtin_amdgcn_s_sleep(1);
      }
    }
    __syncthreads();
  }
}

extern "C" void kernel_launch(void* const* d_in, const int* in_sizes, int n_in,
                              void* d_out, int out_size, void* d_ws, size_t ws_size,
                              hipStream_t stream){
  (void)in_sizes; (void)n_in; (void)out_size; (void)ws_size;
  const float* A      = (const float*)d_in[0];
  const float* X      = (const float*)d_in[1];
  const float* seqs   = (const float*)d_in[2];
  const int*   seqlen = (const int*)d_in[3];
  const float* h0     = (const float*)d_in[4];
  const float* c0     = (const float*)d_in[5];
  const float* gtw1   = (const float*)d_in[6];
  const float* gtw2   = (const float*)d_in[7];
  const float* gtw3   = (const float*)d_in[8];
  const float* gcnW   = (const float*)d_in[9];
  const float* gcnB   = (const float*)d_in[10];
  const float* lin1W  = (const float*)d_in[11];
  const float* lin1B  = (const float*)d_in[12];
  const float* Wih    = (const float*)d_in[13];
  const float* Whh    = (const float*)d_in[14];
  const float* bihp   = (const float*)d_in[15];
  const float* bhhp   = (const float*)d_in[16];
  const float* scoreW = (const float*)d_in[17];

  char* ws = (char*)d_ws;
  u16* buf0 = (u16*)(ws + 0);
  u16* buf1 = (u16*)(ws + 16777216);
  u16* buf2 = (u16*)(ws + 33554432);
  char* S0  = ws + 50331648;
  float* filt  = (float*)(S0 + 0);
  float* disv  = (float*)(S0 + 1024);
  u16*  Wt     = (u16*) (S0 + 17408);
  u16*  XWt    = (u16*) (S0 + 148480);
  u16*  catb   = (u16*) (S0 + 1197056);
  u16*  l1Wt   = (u16*) (S0 + 3294208);
  float* Xo    = (float*)(S0 + 3556352);
  u16*  bs     = (u16*) (S0 + 5653504);
  u16*  act    = (u16*) (S0 + 7357440);    // 128x512 bf16 (rows 64..127 = pad)
  u16*  sWbf   = (u16*) (S0 + 7488512);    // scoreW bf16, 2048x512
  u16*  WhhB   = (u16*) (S0 + 9585664);
  u16*  Xbf    = (u16*) (S0 + 11682816);
  u16*  Wihbf  = (u16*) (S0 + 12731392);
  float* bsum  = (float*)(S0 + 13779968);
  u16*  Hglob  = (u16*) (S0 + 13788160);   // 4 grp x 16384 u16 = 128 KB
  u32*  flagv  = (u32*) (S0 + 13919232);   // 2048 u32
  float* degp  = (float*)(S0 + 14050304);
  float* dinvb = (float*)(S0 + 14312448);  // S0 ends at 14328832
  u16* buf3 = (u16*)(ws + 64660480);       // 16 MiB (total 77.66 MB, r1-proven OK)
  u16* HA   = buf0;
  u16* HBt  = buf1;
  u16* Hb   = buf2;
  u16* HB2t = buf3;
  u16* Pd   = buf1;
  float* Gq = (float*)ws;   // 26.2 MiB over buf0+buf1 (dead by then)

  k_prep0<<<dim3(8), 256, 0, stream>>>(gtw1, gtw2, gtw3, filt, bihp, bhhp, bsum, flagv);
  k_combineAll3<<<dim3(N_/32, N_/32), dim3(32,8), 0, stream>>>(A, filt, HA, HBt, HB2t);
  k_transpose3<<<dim3(16, 64, 2), dim3(32,8), 0, stream>>>(gcnW, Wt, lin1W, l1Wt);
  k_cast3<<<dim3(8192), 256, 0, stream>>>(X, Xbf, Wih, Wihbf, scoreW, sWbf);
  gemm_bt<1><<<dim3(16,16,C_), 256, 0, stream>>>(HA, HBt, Hb, N_, N_, NN_, NN_, NN_, nullptr, 0, nullptr);
  k_degpart<<<dim3(8, 16, C_), 256, 0, stream>>>(Hb, degp);
  k_dinv<<<dim3(16), 256, 0, stream>>>(Hb, degp, dinvb);
  k_colscale<<<dim3(NN_/256, C_), 256, 0, stream>>>(Hb, dinvb);
  k_dis<<<dim3(N_, C_), 256, 0, stream>>>(HB2t, dinvb, disv);
  gemm_bt<5><<<dim3(16,16,C_), 256, 0, stream>>>(HB2t, Hb, Pd, N_, N_, NN_, NN_, NN_, disv, N_, nullptr);
  gemm_bt<1><<<dim3(N_/128, WOUT_/128, 1), 256, 0, stream>>>(Wt, Xbf, XWt, WIN_, N_, 0, 0, 0, nullptr, 0, nullptr);
  gemm_bt<2><<<dim3(WOUT_/128, N_/128, C_), 256, 0, stream>>>(Pd, XWt, catb, N_, C_*WOUT_, NN_, 0, WOUT_, disv, N_, gcnB);
  gemm_bt<3><<<dim3(WOUT_/128, N_/128, 1), 256, 0, stream>>>(catb, l1Wt, Xo, C_*WOUT_, WOUT_, 0, 0, 0, nullptr, 0, lin1B);
  k_pool<<<dim3(52, B_), 256, 0, stream>>>(seqs, Xo, bs);
  gemm_bt<4><<<dim3((4*U_)/128, BTP_/128, 1), 256, 0, stream>>>(bs, Wihbf, Gq, WOUT_, 0, 0, 0, 0, nullptr, 0, bsum);
  k_packWhh3<<<dim3(4096), 256, 0, stream>>>(Whh, WhhB, h0, Hglob);
  k_lstm_all<<<dim3(64), 512, 0, stream>>>(WhhB, Gq, c0, seqlen, Hglob, flagv, act);
  // out = sigmoid(act @ scoreW^T) via MFMA (rows >= 64 discarded)
  gemm_bt<6><<<dim3(N_/128, 1, 1), 256, 0, stream>>>(act, sWbf, (float*)d_out, U_, N_, 0, 0, 0, nullptr, 0, nullptr);
}

// Round 15
// 473.734 us; speedup vs baseline: 7.0474x; 1.0639x over previous
//
#include <hip/hip_runtime.h>
#include <stdint.h>

#define E_ 3
#define C_ 2
#define N_ 2048
#define B_ 64
#define T_ 50
#define WIN_ 256
#define WOUT_ 256
#define U_ 512
#define BT_ (B_*T_)
#define BTP_ 3328

typedef unsigned short u16;
typedef unsigned int u32;
typedef __bf16 bf16x8 __attribute__((ext_vector_type(8)));
typedef float f32x4 __attribute__((ext_vector_type(4)));

#define NN_ (2048LL*2048LL)

__device__ __forceinline__ float bf2f(u16 u){
  u32 x = ((u32)u) << 16; return __builtin_bit_cast(float, x);
}
__device__ __forceinline__ u16 f2bf(float f){
  u32 x = __builtin_bit_cast(u32, f);
  u32 r = (x + 0x7fffu + ((x >> 16) & 1u)) >> 16;
  return (u16)r;
}

__device__ __forceinline__ void gload16(const u16* g, u16* l){
  __builtin_amdgcn_global_load_lds((const __attribute__((address_space(1))) u32*)g,
                                   (__attribute__((address_space(3))) u32*)l, 16, 0, 0);
}

// ---------------- prep0+cast: filters + bsum + flag zero + f32->bf16 casts ----------------
__global__ void k_prep0(const float* __restrict__ w1, const float* __restrict__ w2,
                        const float* __restrict__ w3, float* __restrict__ filt,
                        const float* __restrict__ bih, const float* __restrict__ bhh,
                        float* __restrict__ bsum, u32* __restrict__ flagv,
                        const float* __restrict__ X, u16* __restrict__ Xbf,
                        const float* __restrict__ Wih, u16* __restrict__ Wihbf,
                        const float* __restrict__ scoreW, u16* __restrict__ sWbf){
  const long bx = blockIdx.x;
  if(bx < 8192){
    const long i = bx*256 + threadIdx.x;
    if(i < (long)N_*WIN_) Xbf[i] = f2bf(X[i]);
    else if(i < (long)N_*WIN_ + 4*U_*WOUT_){
      const long j = i - (long)N_*WIN_; Wihbf[j] = f2bf(Wih[j]);
    } else {
      const long j = i - (long)N_*WIN_ - 4*U_*WOUT_; sWbf[j] = f2bf(scoreW[j]);
    }
    return;
  }
  const int i = (int)(bx - 8192)*256 + threadIdx.x;   // 0..2047
  bsum[i] = bih[i] + bhh[i];
  flagv[i] = 0;
  if(i < 3*C_){
    const int fi = i / C_, c = i % C_;
    const float* w = (fi==0) ? w1 : ((fi==1) ? w2 : w3);
    float v[E_]; float mx = -3.4e38f;
    for(int e=0;e<E_;e++){ v[e] = w[c*E_+e]; mx = fmaxf(mx, v[e]); }
    float s = 0.f;
    for(int e=0;e<E_;e++){ v[e] = expf(v[e]-mx); s += v[e]; }
    for(int e=0;e<E_;e++) filt[(fi*C_+c)*E_ + e] = v[e]/s;
  }
}

// ---------------- single-pass combine: HA (direct) + HBt + HB2t (transposed) ----------------
__global__ void k_combineAll3(const float* __restrict__ A, const float* __restrict__ filt,
                              u16* __restrict__ HA, u16* __restrict__ HBt,
                              u16* __restrict__ HB2t){
  __shared__ float te[3][32][33];
  const int ti = blockIdx.x, tj = blockIdx.y;
  const int x = threadIdx.x, y0 = threadIdx.y;
  #pragma unroll
  for(int i=0;i<4;i++){
    const int y = y0 + i*8;
    const long base = (long)(tj*32+y)*N_ + ti*32 + x;
    const float a0 = A[0*NN_+base], a1 = A[1*NN_+base], a2 = A[2*NN_+base];
    te[0][y][x]=a0; te[1][y][x]=a1; te[2][y][x]=a2;
    #pragma unroll
    for(int c=0;c<C_;c++)
      HA[c*NN_ + base] = f2bf(filt[c*E_]*a0 + filt[c*E_+1]*a1 + filt[c*E_+2]*a2);
  }
  __syncthreads();
  #pragma unroll
  for(int i=0;i<4;i++){
    const int y = y0 + i*8;
    const long ob = (long)(ti*32+y)*N_ + tj*32 + x;
    const float a0=te[0][x][y], a1=te[1][x][y], a2=te[2][x][y];
    #pragma unroll
    for(int c=0;c<C_;c++){
      HBt[c*NN_+ob]  = f2bf(filt[(C_+c)*E_]*a0   + filt[(C_+c)*E_+1]*a1   + filt[(C_+c)*E_+2]*a2);
      HB2t[c*NN_+ob] = f2bf(filt[(2*C_+c)*E_]*a0 + filt[(2*C_+c)*E_+1]*a1 + filt[(2*C_+c)*E_+2]*a2);
    }
  }
}

// ---------------- MFMA GEMM (BK=64, double-buffered, prefetch-overlap) ----------------
// OUT[i][j] = sum_k A[i][k]*B[j][k]; LDS chunk q of row r at slot q^(r&7) (pre-swizzled src).
// MODE 1: bf16 raw; 2: bf16 relu(dis[row]*acc+bias[col]); 3: f32 acc+bias[col];
// MODE 4: Gq scatter; MODE 5: bf16 (acc+(row==col))*disv[col]; MODE 6: f32 sigmoid, row<B_;
// MODE 7: split-K f32 partials — z = c*4+ks, slice len = sDis, out[z][row][col(256)]
template<int MODE>
__global__ __launch_bounds__(256) void gemm_bt(
    const u16* __restrict__ Ag, const u16* __restrict__ Bg, void* __restrict__ Cg,
    int K, int ldc, long sA, long sB, long sC,
    const float* __restrict__ disv, int sDis, const float* __restrict__ bias)
{
  __shared__ u16 At[2][128*64];
  __shared__ u16 Bt[2][128*64];
  const int tid = threadIdx.x;
  const int w = tid >> 6, l = tid & 63;
  const int z = blockIdx.z;
  const int zc = (MODE==7) ? (z >> 2) : z;
  const int kBase = (MODE==7) ? ((z & 3)*sDis) : 0;
  const u16* Ab = Ag + (long)zc*sA;
  const u16* Bb = Bg + (long)z*sB;
  const int rowBase = blockIdx.y*128;
  const int colBase = blockIdx.x*128;

  f32x4 acc[4][4];
  #pragma unroll
  for(int i=0;i<4;i++)
    #pragma unroll
    for(int j=0;j<4;j++)
      acc[i][j] = f32x4{0.f,0.f,0.f,0.f};

  const int wr = w >> 1, wc = w & 1;
  const int srow = l >> 3;                       // 0..7 within chunk
  const int scol = ((l & 7) ^ srow) << 3;        // pre-swizzled source col
  const int frow = l & 15;
  const int fkc = l >> 4;                        // 0..3

  const int nk = (MODE==7) ? (sDis >> 6) : (K >> 6);
  // prologue: stage tile 0 into buffer 0
  #pragma unroll
  for(int r=0;r<4;r++){
    const int ch = w*4 + r;
    gload16(Ab + (long)(rowBase + ch*8 + srow)*K + kBase + scol, &At[0][ch*512]);
    gload16(Bb + (long)(colBase + ch*8 + srow)*K + kBase + scol, &Bt[0][ch*512]);
  }
  __syncthreads();                               // tile 0 resident

  for(int kt=0; kt<nk; ++kt){
    const int cur = kt & 1;
    // issue next tile's staging BEFORE compute — overlaps with MFMA below
    if(kt+1 < nk){
      const int k0 = kBase + ((kt+1) << 6);
      #pragma unroll
      for(int r=0;r<4;r++){
        const int ch = w*4 + r;
        gload16(Ab + (long)(rowBase + ch*8 + srow)*K + k0 + scol, &At[cur^1][ch*512]);
        gload16(Bb + (long)(colBase + ch*8 + srow)*K + k0 + scol, &Bt[cur^1][ch*512]);
      }
    }
    #pragma unroll
    for(int ks=0; ks<2; ++ks){
      bf16x8 af[4], bfv[4];
      #pragma unroll
      for(int m=0;m<4;m++){
        const int rr = wr*64 + m*16 + frow;
        af[m] = *(const bf16x8*)&At[cur][rr*64 + (((ks*4 + fkc) ^ (rr&7))<<3)];
      }
      #pragma unroll
      for(int n=0;n<4;n++){
        const int rr = wc*64 + n*16 + frow;
        bfv[n] = *(const bf16x8*)&Bt[cur][rr*64 + (((ks*4 + fkc) ^ (rr&7))<<3)];
      }
      #pragma unroll
      for(int m=0;m<4;m++)
        #pragma unroll
        for(int n=0;n<4;n++)
          acc[m][n] = __builtin_amdgcn_mfma_f32_16x16x32_bf16(af[m], bfv[n], acc[m][n], 0, 0, 0);
    }
    if(kt+1 < nk) __syncthreads();
  }

  #pragma unroll
  for(int m=0;m<4;m++){
    const int row0 = rowBase + wr*64 + m*16 + (l>>4)*4;
    #pragma unroll
    for(int n=0;n<4;n++){
      const int col = colBase + wc*64 + n*16 + (l&15);
      #pragma unroll
      for(int r=0;r<4;r++){
        const float v = acc[m][n][r];
        if(MODE==1){
          ((u16*)Cg)[z*sC + (long)(row0+r)*ldc + col] = f2bf(v);
        } else if(MODE==2){
          float o = disv[z*(long)sDis + row0 + r]*v + bias[col];
          o = o > 0.f ? o : 0.f;
          ((u16*)Cg)[z*sC + (long)(row0+r)*ldc + col] = f2bf(o);
        } else if(MODE==3){
          ((float*)Cg)[z*sC + (long)(row0+r)*ldc + col] = v + bias[col];
        } else if(MODE==4){
          const int row = row0 + r;
          if(row < BT_){
            const int bb = row/50, tt = row - bb*50;
            const int gate = col >> 9, ugg = col & 511;
            ((float*)Cg)[((((long)tt*4 + (bb>>4))*512 + ugg)*16 + (bb&15))*4 + gate] = v + bias[col];
          }
        } else if(MODE==5){
          const int row = row0 + r;
          const float o = (v + (row==col ? 1.f : 0.f)) * disv[z*(long)sDis + col];
          ((u16*)Cg)[z*sC + (long)row*ldc + col] = f2bf(o);
        } else if(MODE==6){
          const int row = row0 + r;
          if(row < B_)
            ((float*)Cg)[(long)row*ldc + col] = 1.f/(1.f + expf(-v));
        } else if(MODE==7){
          ((float*)Cg)[((long)z*N_ + row0 + r)*WOUT_ + col] = v;
        }
      }
    }
  }
}

// ---------------- catred: catb[row][c*256+f] = relu(dis[c][row]*sum4(P) + gcnB[f]) ----------------
__global__ void k_catred(const float* __restrict__ P, const float* __restrict__ disv,
                         const float* __restrict__ gcnB, u16* __restrict__ catb){
  const int idx = blockIdx.x*256 + threadIdx.x;   // 0..1048575
  const int row = idx >> 9;
  const int cf  = idx & 511;
  const int c = cf >> 8, f = cf & 255;
  float s = 0.f;
  #pragma unroll
  for(int ks=0;ks<4;ks++)
    s += P[(((long)(c*4+ks)*N_ + row)<<8) + f];
  float o = disv[c*N_ + row]*s + gcnB[f];
  catb[(long)row*(C_*WOUT_) + cf] = f2bf(o > 0.f ? o : 0.f);
}

// ---------------- column-degree partial sums ----------------
__global__ void k_degpart(const u16* __restrict__ H, float* __restrict__ partial){
  const int c = blockIdx.z;
  const int col = blockIdx.x*256 + threadIdx.x;
  const int r0 = blockIdx.y*128;
  const u16* Hc = H + c*NN_;
  float s = 0.f;
  #pragma unroll 4
  for(int r=0;r<128;r++) s += bf2f(Hc[(long)(r0+r)*N_ + col]);
  partial[((long)c*16 + blockIdx.y)*N_ + col] = s;
}

// ---------------- dinv[c][m] = 1/(colsum - diag), guarded ----------------
__global__ void k_dinv(const u16* __restrict__ H, const float* __restrict__ partial,
                       float* __restrict__ dinvb){
  const int i = blockIdx.x*256 + threadIdx.x;
  const int c = i >> 11, m = i & (N_-1);
  float s = 0.f;
  #pragma unroll
  for(int p=0;p<16;p++) s += partial[((long)c*16 + p)*N_ + m];
  s -= bf2f(H[c*NN_ + (long)m*N_ + m]);
  dinvb[i] = s > 0.f ? 1.f/s : 0.f;
}

// ---------------- merged: colscale (x<16384) | dis row-reduce (x>=16384) ----------------
__global__ void k_colscale_dis(u16* __restrict__ H, const float* __restrict__ dinvb,
                               const u16* __restrict__ HB2t, float* __restrict__ disv){
  const int c = blockIdx.y;
  if(blockIdx.x < 16384){
    const long i = (long)blockIdx.x*256 + threadIdx.x;
    const int j = (int)(i >> 11), ii = (int)(i & (N_-1));
    const long idx = c*NN_ + i;
    const float v = (j==ii) ? 0.f : bf2f(H[idx])*dinvb[c*N_ + ii];
    H[idx] = f2bf(v);
    return;
  }
  const int j = blockIdx.x - 16384;
  const u16* r = HB2t + (c*(long)N_ + j)*N_;
  const float* dv = dinvb + c*N_;
  float s = 0.f;
  for(int i=threadIdx.x;i<N_;i+=256)
    if(dv[i] > 0.f) s += bf2f(r[i]);
  __shared__ float red[256];
  red[threadIdx.x] = s;
  __syncthreads();
  for(int st=128; st>0; st>>=1){
    if(threadIdx.x < st) red[threadIdx.x] += red[threadIdx.x+st];
    __syncthreads();
  }
  if(threadIdx.x==0){
    const float deg = red[0] + 1.f;
    disv[c*N_ + j] = deg > 0.f ? rsqrtf(deg) : 0.f;
  }
}

// ---------------- 2-in-1 transpose f32 -> bf16 ----------------
__global__ void k_transpose3(const float* __restrict__ gcnW, u16* __restrict__ Wt,
                             const float* __restrict__ lin1W, u16* __restrict__ l1Wt){
  const float* in; u16* out; int R, Cc;
  if(blockIdx.z==0){ in=gcnW;  out=Wt;   R=WIN_;     Cc=WOUT_; }
  else { in=lin1W; out=l1Wt; R=C_*WOUT_; Cc=WOUT_; }
  const int ti = blockIdx.x, tj = blockIdx.y;
  if(ti >= (Cc>>5) || tj >= (R>>5)) return;
  __shared__ float tt[32][33];
  const int x = threadIdx.x, y0 = threadIdx.y;
  #pragma unroll
  for(int i=0;i<4;i++){
    const int y = y0 + i*8;
    tt[y][x] = in[(long)(tj*32+y)*Cc + ti*32 + x];
  }
  __syncthreads();
  #pragma unroll
  for(int i=0;i<4;i++){
    const int y = y0 + i*8;
    out[(long)(ti*32+y)*R + tj*32 + x] = f2bf(tt[x][y]);
  }
}

// ---------------- basket max-pool (grid 52x64; t>=50 writes pad zeros) ----------------
__global__ void k_pool(const float* __restrict__ seqs, const float* __restrict__ X_,
                       u16* __restrict__ bs){
  const int t = blockIdx.x, b = blockIdx.y;
  const int f = threadIdx.x;
  if(t >= T_){
    bs[(long)(BT_ + b*2 + (t-T_))*WOUT_ + f] = 0;
    return;
  }
  const float* mask = seqs + ((long)b*T_ + t)*N_;
  __shared__ int list[N_];
  __shared__ int cnt;
  if(f==0) cnt = 0;
  __syncthreads();
  // vectorized sweep: thread f owns elements [f*8, f*8+8)
  {
    const float4 m0 = *(const float4*)&mask[f*8];
    const float4 m1 = *(const float4*)&mask[f*8+4];
    const float mv[8] = {m0.x,m0.y,m0.z,m0.w,m1.x,m1.y,m1.z,m1.w};
    #pragma unroll
    for(int q=0;q<8;q++){
      if(mv[q] > 0.f){
        int p = atomicAdd(&cnt, 1);
        list[p] = f*8 + q;
      }
    }
  }
  __syncthreads();
  const int m = cnt;
  float mx = -3.4e38f;
  for(int i=0;i<m;i++)
    mx = fmaxf(mx, X_[(long)list[i]*WOUT_ + f]);
  bs[((long)b*T_ + t)*WOUT_ + f] = f2bf(m>0 ? mx : 0.f);
}

// ---------------- pack Whh (r8 layout) + fused Hglob init ----------------
__global__ void k_packWhh3(const float* __restrict__ Whh, u16* __restrict__ P,
                           const float* __restrict__ h0, u16* __restrict__ Hglob){
  const long idx = (long)blockIdx.x*256 + threadIdx.x;
  const int e  = (int)(idx & 7);
  const int kk = (int)((idx >> 3) & 15);
  const int l  = (int)((idx >> 7) & 63);
  const int w  = (int)((idx >> 13) & 7);
  const int s  = (int)(idx >> 16);
  const int lr = w*16 + (l & 15);
  const int gam = lr & 3, ui = lr >> 2;
  const int grow = gam*512 + s*32 + ui;
  const int k = kk*32 + (l >> 4)*8 + e;
  P[idx] = f2bf(Whh[(long)grow*512 + k]);
  if(idx < 32768){
    const int b = (int)(idx >> 9), u = (int)(idx & 511);
    const int grp = b >> 4, bl = b & 15;
    Hglob[grp*16384 + (bl << 9) + (u ^ ((bl & 7) << 3))] = f2bf(h0[idx]);
  }
}

// ---------------- persistent LSTM (r8-proven): 4 XCD-affine groups x 16 blocks ----------------
__global__ __launch_bounds__(512) void k_lstm_all(
    const u16* __restrict__ WhhP, const float* __restrict__ Gq,
    const float* __restrict__ c0v, const int* __restrict__ seqlen,
    u16* __restrict__ Hglob, u32* __restrict__ flagv, u16* __restrict__ act)
{
  __shared__ u16 Hl[16*512];
  const int tid = threadIdx.x;
  const int w = tid >> 6, l = tid & 63;
  const int grp = blockIdx.x & 3, s = blockIdx.x >> 2;
  const int fr = l & 15, hi = l >> 4;

  bf16x8 wreg[16];
  const u16* wp = WhhP + (((long)s*8 + w)*64 + l)*128;
  #pragma unroll
  for(int kk=0; kk<16; ++kk)
    wreg[kk] = *(const bf16x8*)&wp[kk*8];

  const int ug = s*32 + w*4 + hi;
  const int bl = fr;
  const int bg = grp*16 + bl;
  float cst = c0v[bg*U_ + ug];
  const int sl = seqlen[bg] - 1;
  u16* Hbase = Hglob + grp*16384;
  const int hswz = (bl & 7) << 3;
  const int fi = (grp*16 + fr)*32;
  const long gqbase = (((long)grp*512 + ug)*16 + bl)*4;
  float4 gq_nxt = *(const float4*)&Gq[gqbase];

  for(int t=0; t<T_; ++t){
    const float4 gq = gq_nxt;
    const u16* Hin = Hbase + (t & 1)*8192;
    #pragma unroll
    for(int r=0; r<2; ++r)
      gload16(Hin + (r*8 + w)*512 + l*8, &Hl[(r*8 + w)*512]);
    __syncthreads();

    f32x4 acc = f32x4{0.f,0.f,0.f,0.f};
    #pragma unroll
    for(int kk=0; kk<16; ++kk){
      const int ke = kk*32 + hi*8;
      bf16x8 bb = *(const bf16x8*)&Hl[(bl << 9) + (ke ^ hswz)];
      acc = __builtin_amdgcn_mfma_f32_16x16x32_bf16(wreg[kk], bb, acc, 0, 0, 0);
    }

    if(t+1 < T_)
      gq_nxt = *(const float4*)&Gq[(long)(t+1)*(4*2048*16) + gqbase];

    const float a0 = acc[0] + gq.x;
    const float a1 = acc[1] + gq.y;
    const float a2 = acc[2] + gq.z;
    const float a3 = acc[3] + gq.w;
    const float ig = 1.f/(1.f + expf(-a0));
    const float fg = 1.f/(1.f + expf(-a1));
    const float gg = tanhf(a2);
    const float og = 1.f/(1.f + expf(-a3));
    cst = fg*cst + ig*gg;
    const float h = og*tanhf(cst);
    u16* Hout = Hbase + ((t+1) & 1)*8192;
    Hout[(bl << 9) + (ug ^ hswz)] = f2bf(h);
    if(sl == t) act[bg*U_ + ug] = f2bf(h);

    if(t == T_-1) break;
    __syncthreads();
    if(tid == 0)
      __hip_atomic_store(&flagv[(grp*16 + s)*32], (u32)(t+1),
                         __ATOMIC_RELEASE, __HIP_MEMORY_SCOPE_AGENT);
    if(w == 0){
      while(__hip_atomic_load(&flagv[fi], __ATOMIC_ACQUIRE,
                              __HIP_MEMORY_SCOPE_AGENT) <= (u32)t){
        __builtin_amdgcn_s_sleep(1);
      }
    }
    __syncthreads();
  }
}

extern "C" void kernel_launch(void* const* d_in, const int* in_sizes, int n_in,
                              void* d_out, int out_size, void* d_ws, size_t ws_size,
                              hipStream_t stream){
  (void)in_sizes; (void)n_in; (void)out_size; (void)ws_size;
  const float* A      = (const float*)d_in[0];
  const float* X      = (const float*)d_in[1];
  const float* seqs   = (const float*)d_in[2];
  const int*   seqlen = (const int*)d_in[3];
  const float* h0     = (const float*)d_in[4];
  const float* c0     = (const float*)d_in[5];
  const float* gtw1   = (const float*)d_in[6];
  const float* gtw2   = (const float*)d_in[7];
  const float* gtw3   = (const float*)d_in[8];
  const float* gcnW   = (const float*)d_in[9];
  const float* gcnB   = (const float*)d_in[10];
  const float* lin1W  = (const float*)d_in[11];
  const float* lin1B  = (const float*)d_in[12];
  const float* Wih    = (const float*)d_in[13];
  const float* Whh    = (const float*)d_in[14];
  const float* bihp   = (const float*)d_in[15];
  const float* bhhp   = (const float*)d_in[16];
  const float* scoreW = (const float*)d_in[17];

  char* ws = (char*)d_ws;
  u16* buf0 = (u16*)(ws + 0);
  u16* buf1 = (u16*)(ws + 16777216);
  u16* buf2 = (u16*)(ws + 33554432);
  char* S0  = ws + 50331648;
  float* filt  = (float*)(S0 + 0);
  float* disv  = (float*)(S0 + 1024);
  u16*  Wt     = (u16*) (S0 + 17408);
  u16*  XWt    = (u16*) (S0 + 148480);
  u16*  catb   = (u16*) (S0 + 1197056);
  u16*  l1Wt   = (u16*) (S0 + 3294208);
  float* Xo    = (float*)(S0 + 3556352);
  u16*  bs     = (u16*) (S0 + 5653504);
  u16*  act    = (u16*) (S0 + 7357440);    // 128x512 bf16 (rows 64..127 = pad)
  u16*  sWbf   = (u16*) (S0 + 7488512);    // scoreW bf16, 2048x512
  u16*  WhhB   = (u16*) (S0 + 9585664);
  u16*  Xbf    = (u16*) (S0 + 11682816);
  u16*  Wihbf  = (u16*) (S0 + 12731392);
  float* bsum  = (float*)(S0 + 13779968);
  u16*  Hglob  = (u16*) (S0 + 13788160);   // 4 grp x 16384 u16 = 128 KB
  u32*  flagv  = (u32*) (S0 + 13919232);   // 2048 u32
  float* degp  = (float*)(S0 + 14050304);
  float* dinvb = (float*)(S0 + 14312448);  // S0 ends at 14328832
  u16* buf3 = (u16*)(ws + 64660480);       // 16 MiB (total 77.66 MB, r1-proven OK)
  u16* HA   = buf0;
  u16* HBt  = buf1;
  u16* Hb   = buf2;
  u16* HB2t = buf3;
  u16* Pd   = buf1;
  float* Pcat = (float*)ws;                // 16.78 MB catb partials over buf0 (HA dead)
  float* Gq = (float*)ws;                  // 26.2 MiB over buf0+buf1 (dead by then)

  k_prep0<<<dim3(8200), 256, 0, stream>>>(gtw1, gtw2, gtw3, filt, bihp, bhhp, bsum, flagv,
                                          X, Xbf, Wih, Wihbf, scoreW, sWbf);
  k_combineAll3<<<dim3(N_/32, N_/32), dim3(32,8), 0, stream>>>(A, filt, HA, HBt, HB2t);
  k_transpose3<<<dim3(16, 64, 2), dim3(32,8), 0, stream>>>(gcnW, Wt, lin1W, l1Wt);
  gemm_bt<1><<<dim3(16,16,C_), 256, 0, stream>>>(HA, HBt, Hb, N_, N_, NN_, NN_, NN_, nullptr, 0, nullptr);
  k_degpart<<<dim3(8, 16, C_), 256, 0, stream>>>(Hb, degp);
  k_dinv<<<dim3(16), 256, 0, stream>>>(Hb, degp, dinvb);
  k_colscale_dis<<<dim3(16384 + N_, C_), 256, 0, stream>>>(Hb, dinvb, HB2t, disv);
  gemm_bt<5><<<dim3(16,16,C_), 256, 0, stream>>>(HB2t, Hb, Pd, N_, N_, NN_, NN_, NN_, disv, N_, nullptr);
  gemm_bt<1><<<dim3(N_/128, WOUT_/128, 1), 256, 0, stream>>>(Wt, Xbf, XWt, WIN_, N_, 0, 0, 0, nullptr, 0, nullptr);
  // catb via split-K=4: f32 partials into Pcat (buf0, dead), then fused reduce
  gemm_bt<7><<<dim3(WOUT_/128, N_/128, C_*4), 256, 0, stream>>>(Pd, XWt, Pcat, N_, 0, NN_, 0, 0, nullptr, 512, nullptr);
  k_catred<<<dim3(4096), 256, 0, stream>>>(Pcat, disv, gcnB, catb);
  gemm_bt<3><<<dim3(WOUT_/128, N_/128, 1), 256, 0, stream>>>(catb, l1Wt, Xo, C_*WOUT_, WOUT_, 0, 0, 0, nullptr, 0, lin1B);
  k_pool<<<dim3(52, B_), 256, 0, stream>>>(seqs, Xo, bs);
  gemm_bt<4><<<dim3((4*U_)/128, BTP_/128, 1), 256, 0, stream>>>(bs, Wihbf, Gq, WOUT_, 0, 0, 0, 0, nullptr, 0, bsum);
  k_packWhh3<<<dim3(4096), 256, 0, stream>>>(Whh, WhhB, h0, Hglob);
  k_lstm_all<<<dim3(64), 512, 0, stream>>>(WhhB, Gq, c0, seqlen, Hglob, flagv, act);
  // out = sigmoid(act @ scoreW^T) via MFMA (rows >= 64 discarded)
  gemm_bt<6><<<dim3(N_/128, 1, 1), 256, 0, stream>>>(act, sWbf, (float*)d_out, U_, N_, 0, 0, 0, nullptr, 0, nullptr);
}